// Round 8
// baseline (657.179 us; speedup 1.0000x reference)
//
#include <hip/hip_runtime.h>
#include <hip/hip_bf16.h>

#define NXD   100000
#define AROWS 50000
#define NND   200000   // total nodes
#define EED   2000000  // given edges
#define ETOT  2200000  // + self loops
#define GHD   13
#define MMD   1024

#define OUT_H1 16384
#define OUT_H2 (16384 + AROWS * GHD)

#define NB    196      // buckets for CSR build (1024 nodes each)
#define BSH   10
#define CAP   16000    // staging capacity per bucket (mean 11264)
#define TILE  4096     // edges per bin-pass block (538 blocks)

typedef __hip_bfloat16 bf16;
typedef unsigned int uvec4 __attribute__((ext_vector_type(4)));

__device__ __forceinline__ float bf2f(bf16 v) { return __bfloat162float(v); }
__device__ __forceinline__ float sigm(float x) { return 1.f / (1.f + __expf(-x)); }
__device__ __forceinline__ float tanhfast(float x) {
    x = fminf(15.f, fmaxf(-15.f, x));
    float t = __expf(-2.f * x);
    return (1.f - t) / (1.f + t);
}
__device__ __forceinline__ float lrelu(float x, float s) { return x > 0.f ? x : s * x; }

__device__ __forceinline__ unsigned short f2bf_bits(float v) {
    bf16 b = __float2bfloat16(v);
    return *reinterpret_cast<unsigned short*>(&b);
}
__device__ __forceinline__ float bflo(unsigned int u) { return __uint_as_float((u & 0xFFFFu) << 16); }
__device__ __forceinline__ float bfhi(unsigned int u) { return __uint_as_float(u & 0xFFFF0000u); }

// Generic input load / output store: f32 flag picks fp32 vs bf16 interpretation.
__device__ __forceinline__ float loadF(const void* p, size_t i, int f32) {
    return f32 ? ((const float*)p)[i] : bf2f(((const bf16*)p)[i]);
}
__device__ __forceinline__ void storeF(void* p, size_t i, float v, int f32) {
    if (f32) ((float*)p)[i] = v;
    else ((bf16*)p)[i] = __float2bfloat16(v);
}

// ---------------- dtype detection + gtail zero ----------------
__global__ void detect_kernel(const void* __restrict__ xp, int* __restrict__ flag,
                              int* __restrict__ gtail) {
    int lane = threadIdx.x;  // 64
    const unsigned short* u = (const unsigned short*)xp;
    unsigned short b = u[lane * 2];
    int e = (b >> 7) & 0xFF;
    int viol = (e == 0xFF) || (e < 64) || (e > 190);
    unsigned long long mask = __ballot(viol != 0);
    if (lane == 0) flag[0] = (__popcll(mask) > 8) ? 1 : 0;  // 1 => fp32 inputs
    for (int i = lane; i < NB; i += 64) gtail[i] = 0;
}

// ---------------- x rows + prefix columns into bufA ----------------
__global__ void assemble_kernel(const void* __restrict__ x, const void* __restrict__ prefix,
                                bf16* __restrict__ bufA, const int* __restrict__ flag) {
    int f = *flag;
    int t = blockIdx.x * 256 + threadIdx.x;
    if (t < NXD * 16) {
        bufA[t] = __float2bfloat16(loadF(x, t, f));
    } else {
        int u = t - NXD * 16;
        if (u < NXD * 3) {
            int r = u / 3, c = u - r * 3;
            bufA[(size_t)(NXD + r) * 16 + c] = __float2bfloat16(loadF(prefix, u, f));
        }
    }
}

// ---------------- both GRUs in one kernel (50000 rows each, in=1, hidden=13) ----------------
__global__ void gru2_kernel(const void* __restrict__ msg1, const void* __restrict__ hid1,
                            const void* __restrict__ Wih1, const void* __restrict__ Whh1,
                            const void* __restrict__ bih1, const void* __restrict__ bhh1,
                            const void* __restrict__ msg2, const void* __restrict__ hid2,
                            const void* __restrict__ Wih2, const void* __restrict__ Whh2,
                            const void* __restrict__ bih2, const void* __restrict__ bhh2,
                            void* __restrict__ dout, bf16* __restrict__ xxA,
                            const int* __restrict__ flag) {
    int f = *flag;
    int which = blockIdx.x >= 196;
    const void* msg = which ? msg2 : msg1;
    const void* hid = which ? hid2 : hid1;
    const void* Wih = which ? Wih2 : Wih1;
    const void* Whh = which ? Whh2 : Whh1;
    const void* bih = which ? bih2 : bih1;
    const void* bhh = which ? bhh2 : bhh1;
    size_t houtbase = which ? (size_t)OUT_H2 : (size_t)OUT_H1;
    int rowbase = which ? AROWS : 0;
    int blk = blockIdx.x - (which ? 196 : 0);
    __shared__ float WhhL[39 * 13], WihL[39], bihL[39], bhhL[39];
    int tid = threadIdx.x;
    for (int i = tid; i < 39 * 13; i += 256) WhhL[i] = loadF(Whh, i, f);
    if (tid < 39) { WihL[tid] = loadF(Wih, tid, f); bihL[tid] = loadF(bih, tid, f); bhhL[tid] = loadF(bhh, tid, f); }
    __syncthreads();
    int n = blk * 256 + tid;
    if (n >= AROWS) return;
    float x = loadF(msg, n, f);
    float h[GHD];
#pragma unroll
    for (int k = 0; k < GHD; k++) h[k] = loadF(hid, n * GHD + k, f);
#pragma unroll
    for (int k = 0; k < GHD; k++) {
        float gir = fmaf(x, WihL[k],      bihL[k]);
        float giz = fmaf(x, WihL[13 + k], bihL[13 + k]);
        float gin = fmaf(x, WihL[26 + k], bihL[26 + k]);
        float ghr = bhhL[k], ghz = bhhL[13 + k], ghn = bhhL[26 + k];
#pragma unroll
        for (int q = 0; q < GHD; q++) {
            ghr = fmaf(h[q], WhhL[k * 13 + q],        ghr);
            ghz = fmaf(h[q], WhhL[(13 + k) * 13 + q], ghz);
            ghn = fmaf(h[q], WhhL[(26 + k) * 13 + q], ghn);
        }
        float r = sigm(gir + ghr);
        float z = sigm(giz + ghz);
        float nn = tanhfast(gin + r * ghn);
        float o = (1.f - z) * nn + z * h[k];
        storeF(dout, houtbase + (size_t)n * GHD + k, o, f);
        xxA[(size_t)(NXD + rowbase + n) * 16 + 3 + k] = __float2bfloat16(o);
    }
}

// ---------------- CSR build: bin pass ----------------
__global__ void bin_kernel(const int* __restrict__ src_e, const int* __restrict__ dst_e,
                           int* __restrict__ gtail, unsigned int* __restrict__ stage) {
    __shared__ int hist[NB];
    __shared__ int base[NB];
    __shared__ int cur[NB];
    int tid = threadIdx.x;
    for (int i = tid; i < NB; i += 256) hist[i] = 0;
    __syncthreads();
    int t0 = blockIdx.x * TILE;
    int tend = t0 + TILE; if (tend > ETOT) tend = ETOT;
    for (int t = t0 + tid; t < tend; t += 256) {
        int d = (t < EED) ? dst_e[t] : (t - EED);
        atomicAdd(&hist[d >> BSH], 1);
    }
    __syncthreads();
    for (int i = tid; i < NB; i += 256) {
        int c = hist[i];
        base[i] = (c > 0) ? atomicAdd(&gtail[i], c) : 0;
        cur[i] = 0;
    }
    __syncthreads();
    for (int t = t0 + tid; t < tend; t += 256) {
        int s, d;
        if (t < EED) { s = src_e[t]; d = dst_e[t]; } else { s = d = t - EED; }
        int b = d >> BSH;
        int p = base[b] + atomicAdd(&cur[b], 1);
        if (p < CAP)
            stage[(size_t)b * CAP + p] = ((unsigned int)(d & 1023) << 18) | (unsigned int)s;
    }
}

// ---------------- CSR build: per-bucket placement (ebase computed in-kernel) ----------------
__global__ void build_kernel(const unsigned int* __restrict__ stage,
                             const int* __restrict__ gtail,
                             int* __restrict__ offs, int* __restrict__ csr) {
    __shared__ int cnt[1024];
    __shared__ int loc[1024];
    __shared__ int cur[1024];
    __shared__ int lds[256];
    int b = blockIdx.x;
    int tid = threadIdx.x;
    // exclusive prefix of gtail to get this bucket's edge base (all blocks redundantly)
    int v = (tid < NB) ? gtail[tid] : 0;
    lds[tid] = v; __syncthreads();
    for (int off = 1; off < 256; off <<= 1) {
        int t2 = (tid >= off) ? lds[tid - off] : 0;
        __syncthreads();
        lds[tid] += t2;
        __syncthreads();
    }
    __shared__ int ebs;
    if (tid == b) ebs = lds[tid] - v;
    __syncthreads();
    int eb = ebs;
    int nE = gtail[b]; if (nE > CAP) nE = CAP;
    const unsigned int* st = stage + (size_t)b * CAP;
    for (int i = tid; i < 1024; i += 256) cnt[i] = 0;
    __syncthreads();
    for (int i = tid; i < nE; i += 256)
        atomicAdd(&cnt[st[i] >> 18], 1);
    __syncthreads();
    int c0 = cnt[tid * 4], c1 = cnt[tid * 4 + 1], c2 = cnt[tid * 4 + 2], c3 = cnt[tid * 4 + 3];
    int s = c0 + c1 + c2 + c3;
    lds[tid] = s; __syncthreads();
    for (int off = 1; off < 256; off <<= 1) {
        int t2 = (tid >= off) ? lds[tid - off] : 0;
        __syncthreads();
        lds[tid] += t2;
        __syncthreads();
    }
    int run = lds[tid] - s;
    loc[tid * 4]     = run;
    loc[tid * 4 + 1] = run + c0;
    loc[tid * 4 + 2] = run + c0 + c1;
    loc[tid * 4 + 3] = run + c0 + c1 + c2;
    __syncthreads();
    int nodebase = b << BSH;
    for (int i = tid; i < 1024; i += 256) {
        cur[i] = loc[i];
        int n = nodebase + i;
        if (n < NND) offs[n] = eb + loc[i];
    }
    if (b == 0 && tid == 0) offs[NND] = ETOT;
    __syncthreads();
    for (int i = tid; i < nE; i += 256) {
        unsigned int e = st[i];
        int dl = e >> 18;
        int src = e & 0x3FFFF;
        int p = atomicAdd(&cur[dl], 1);
        csr[eb + p] = src;
    }
}

// ---------------- per-layer features: h = xx@W, as_, ad ----------------
template <int K>
__global__ void feat_kernel(const bf16* __restrict__ xx,
                            const void* __restrict__ W,
                            const void* __restrict__ asrc,
                            const void* __restrict__ adst,
                            bf16* __restrict__ hbuf, float* __restrict__ asb,
                            float* __restrict__ adb, const int* __restrict__ flag) {
    int f = *flag;
    __shared__ float Wl[K * 32];
    __shared__ float asl[32], adl[32];
    int tid = threadIdx.x;
    for (int i = tid; i < K * 32; i += 256) Wl[i] = loadF(W, i, f);
    if (tid < 32) { asl[tid] = loadF(asrc, tid, f); adl[tid] = loadF(adst, tid, f); }
    __syncthreads();
    int n = blockIdx.x * 8 + (tid >> 5);
    int j = tid & 31;
    const uvec4* xr4 = (const uvec4*)(xx + (size_t)n * K);
    float v = 0.f;
#pragma unroll
    for (int q = 0; q < K / 8; q++) {
        uvec4 u = xr4[q];
        v = fmaf(bflo(u.x), Wl[(q * 8 + 0) * 32 + j], v);
        v = fmaf(bfhi(u.x), Wl[(q * 8 + 1) * 32 + j], v);
        v = fmaf(bflo(u.y), Wl[(q * 8 + 2) * 32 + j], v);
        v = fmaf(bfhi(u.y), Wl[(q * 8 + 3) * 32 + j], v);
        v = fmaf(bflo(u.z), Wl[(q * 8 + 4) * 32 + j], v);
        v = fmaf(bfhi(u.z), Wl[(q * 8 + 5) * 32 + j], v);
        v = fmaf(bflo(u.w), Wl[(q * 8 + 6) * 32 + j], v);
        v = fmaf(bfhi(u.w), Wl[(q * 8 + 7) * 32 + j], v);
    }
    hbuf[(size_t)n * 32 + j] = __float2bfloat16(v);
    int head = j >> 3;
    float ca = v * asl[j];
    float cd = v * adl[j];
#pragma unroll
    for (int m = 1; m < 8; m <<= 1) { ca += __shfl_xor(ca, m); cd += __shfl_xor(cd, m); }
    if ((j & 7) == 0) { asb[n * 4 + head] = ca; adb[n * 4 + head] = cd; }
}

// ---------------- aggregation (layers 1-3): online segment-softmax ----------------
// 4 lanes per node (lane == head), 8 channels/lane via 16B loads,
// 16 node-chains per wave, depth-2 pipeline -> ~32 lines in flight.
// Branchless online softmax; NT csr loads + NT output stores (keep h in L2).
__global__ void agg_kernel(const bf16* __restrict__ hbuf, const float* __restrict__ asb,
                           const float* __restrict__ adb, const int* __restrict__ offs,
                           const int* __restrict__ csr, const void* __restrict__ bias,
                           bf16* __restrict__ xxout, const int* __restrict__ flag) {
    int f = *flag;
    __shared__ float bl[32];
    int tid = threadIdx.x;
    if (tid < 32) bl[tid] = loadF(bias, tid, f);
    __syncthreads();
    int n = blockIdx.x * 64 + (tid >> 2);
    int j = tid & 3;                 // head j, channels 8j..8j+7
    float adv = adb[n * 4 + j];
    int beg = offs[n], end = offs[n + 1];
    int cnt = end - beg;
    const int* cp = csr + beg;
    // preamble (self-loop guarantees cnt >= 1)
    int s0 = __builtin_nontemporal_load(cp);
    float as0 = asb[s0 * 4 + j];
    uvec4 h0 = *(const uvec4*)(hbuf + (size_t)s0 * 32 + 8 * j);
    float as1 = as0; uvec4 h1 = h0;
    if (cnt > 1) {
        int s1 = __builtin_nontemporal_load(cp + 1);
        as1 = asb[s1 * 4 + j];
        h1 = *(const uvec4*)(hbuf + (size_t)s1 * 32 + 8 * j);
    }
    float m = -1e30f, den = 0.f;
    float a0 = 0.f, a1 = 0.f, a2 = 0.f, a3 = 0.f, a4 = 0.f, a5 = 0.f, a6 = 0.f, a7 = 0.f;
    for (int i = 0; i < cnt; i++) {
        float asn = 0.f; uvec4 hn = (uvec4)(0u);
        if (i + 2 < cnt) {
            int sn = __builtin_nontemporal_load(cp + i + 2);
            asn = asb[sn * 4 + j];
            hn = *(const uvec4*)(hbuf + (size_t)sn * 32 + 8 * j);
        }
        float e = as0 + adv;
        e = e > 0.f ? e : 0.2f * e;
        float mn = fmaxf(m, e);
        float sc = __expf(m - mn);
        float w  = __expf(e - mn);
        den = fmaf(den, sc, w);
        a0 = fmaf(a0, sc, w * bflo(h0.x)); a1 = fmaf(a1, sc, w * bfhi(h0.x));
        a2 = fmaf(a2, sc, w * bflo(h0.y)); a3 = fmaf(a3, sc, w * bfhi(h0.y));
        a4 = fmaf(a4, sc, w * bflo(h0.z)); a5 = fmaf(a5, sc, w * bfhi(h0.z));
        a6 = fmaf(a6, sc, w * bflo(h0.w)); a7 = fmaf(a7, sc, w * bfhi(h0.w));
        m = mn;
        as0 = as1; h0 = h1;
        as1 = asn; h1 = hn;
    }
    float inv = 1.f / den;
    int cb = 8 * j;
    float o0 = lrelu(fmaf(a0, inv, bl[cb + 0]), 0.01f);
    float o1 = lrelu(fmaf(a1, inv, bl[cb + 1]), 0.01f);
    float o2 = lrelu(fmaf(a2, inv, bl[cb + 2]), 0.01f);
    float o3 = lrelu(fmaf(a3, inv, bl[cb + 3]), 0.01f);
    float o4 = lrelu(fmaf(a4, inv, bl[cb + 4]), 0.01f);
    float o5 = lrelu(fmaf(a5, inv, bl[cb + 5]), 0.01f);
    float o6 = lrelu(fmaf(a6, inv, bl[cb + 6]), 0.01f);
    float o7 = lrelu(fmaf(a7, inv, bl[cb + 7]), 0.01f);
    uvec4 p;
    p.x = ((unsigned int)f2bf_bits(o1) << 16) | f2bf_bits(o0);
    p.y = ((unsigned int)f2bf_bits(o3) << 16) | f2bf_bits(o2);
    p.z = ((unsigned int)f2bf_bits(o5) << 16) | f2bf_bits(o4);
    p.w = ((unsigned int)f2bf_bits(o7) << 16) | f2bf_bits(o6);
    __builtin_nontemporal_store(p, (uvec4*)(xxout + (size_t)n * 32 + cb));
}

// ---------------- layer 4: only at the 1024 function nodes ----------------
__global__ void layer4_kernel(const bf16* __restrict__ xx,
                              const void* __restrict__ W4,
                              const void* __restrict__ asrc,
                              const void* __restrict__ adst,
                              const void* __restrict__ b4,
                              const int* __restrict__ fidx, const int* __restrict__ offs,
                              const int* __restrict__ csr, float* __restrict__ pool,
                              const int* __restrict__ flag) {
    int f = *flag;
    __shared__ float Wl[32 * 128];
    __shared__ float asl[128], adl[128], bl[32];
    int tid = threadIdx.x;
    for (int i = tid; i < 32 * 128; i += 256) Wl[i] = loadF(W4, i, f);
    if (tid < 128) { asl[tid] = loadF(asrc, tid, f); adl[tid] = loadF(adst, tid, f); }
    if (tid < 32) bl[tid] = loadF(b4, tid, f);
    __syncthreads();
    int wave = tid >> 6, lane = tid & 63;
    int g = blockIdx.x * 4 + wave;
    int d = fidx[g];
    int c = lane & 31;
    int h0 = lane >> 5;
    int h1 = h0 + 2;
    const bf16* xd = xx + (size_t)d * 32;
    float v0 = 0.f, v1 = 0.f;
#pragma unroll
    for (int k = 0; k < 32; k++) {
        float xv = bf2f(xd[k]);
        v0 = fmaf(xv, Wl[k * 128 + lane], v0);
        v1 = fmaf(xv, Wl[k * 128 + lane + 64], v1);
    }
    float ad0 = v0 * adl[h0 * 32 + c];
    float ad1 = v1 * adl[h1 * 32 + c];
#pragma unroll
    for (int mk = 1; mk < 32; mk <<= 1) { ad0 += __shfl_xor(ad0, mk); ad1 += __shfl_xor(ad1, mk); }
    float m0 = -1e30f, den0 = 0.f, acc0 = 0.f;
    float m1 = -1e30f, den1 = 0.f, acc1 = 0.f;
    int beg = offs[d], end = offs[d + 1];
    for (int i = beg; i < end; i++) {
        int s = csr[i];
        const bf16* xs = xx + (size_t)s * 32;
        float s0 = 0.f, s1 = 0.f;
#pragma unroll
        for (int k = 0; k < 32; k++) {
            float xv = bf2f(xs[k]);
            s0 = fmaf(xv, Wl[k * 128 + lane], s0);
            s1 = fmaf(xv, Wl[k * 128 + lane + 64], s1);
        }
        float as0 = s0 * asl[h0 * 32 + c];
        float as1 = s1 * asl[h1 * 32 + c];
#pragma unroll
        for (int mk = 1; mk < 32; mk <<= 1) { as0 += __shfl_xor(as0, mk); as1 += __shfl_xor(as1, mk); }
        float e0 = lrelu(as0 + ad0, 0.2f);
        float e1 = lrelu(as1 + ad1, 0.2f);
        if (e0 <= m0) { float w = __expf(e0 - m0); den0 += w; acc0 = fmaf(w, s0, acc0); }
        else { float sc = __expf(m0 - e0); den0 = fmaf(den0, sc, 1.f); acc0 = fmaf(acc0, sc, s0); m0 = e0; }
        if (e1 <= m1) { float w = __expf(e1 - m1); den1 += w; acc1 = fmaf(w, s1, acc1); }
        else { float sc = __expf(m1 - e1); den1 = fmaf(den1, sc, 1.f); acc1 = fmaf(acc1, sc, s1); m1 = e1; }
    }
    float t = acc0 / den0 + acc1 / den1;
    t += __shfl_xor(t, 32);
    if (lane < 32) {
        float o = t * 0.25f + bl[c];
        pool[g * 32 + c] = lrelu(o, 0.01f);
    }
}

// ---------------- fused final scoring: vq/vk + sq/sk + weights (one block) ----------------
__global__ void tail_kernel(const void* __restrict__ Wq, const void* __restrict__ Wk,
                            const void* __restrict__ Ws, const void* __restrict__ bs,
                            const int* __restrict__ gidx, const int* __restrict__ gsrc,
                            const float* __restrict__ pool, void* __restrict__ out,
                            const int* __restrict__ flag) {
    int f = *flag;
    __shared__ float vq[128], vk[128];
    __shared__ float sq[4096], sk[4096];
    int tid = threadIdx.x;  // 256
    // phase 1: vq/vk
    {
        int which = tid >> 7;
        int i = tid & 127;
        int h = i >> 5, dd = i & 31;
        const void* Wm = which ? Wk : Wq;
        float sum = 0.f;
#pragma unroll
        for (int o = 0; o < 32; o++)
            sum = fmaf(loadF(Wm, (h * 32 + dd) * 32 + o, f), loadF(Ws, h * 64 + which * 32 + o, f), sum);
        (which ? vk : vq)[i] = sum;
    }
    __syncthreads();
    // phase 2: sq/sk
    for (int idx = tid; idx < 8192; idx += 256) {
        int which = idx >> 12;
        int i = idx & 4095;
        int g = i >> 2, h = i & 3;
        const float* V = which ? vk : vq;
        float s = 0.f;
#pragma unroll
        for (int dd = 0; dd < 32; dd++) s = fmaf(pool[g * 32 + dd], V[h * 32 + dd], s);
        (which ? sk : sq)[i] = s;
    }
    __syncthreads();
    // phase 3: weights
    for (int t = tid; t < 4096; t += 256) {
        int g = t >> 2, h = t & 3;
        int i = gidx[g];
        float bsv = loadF(bs, h, f);
        float sqi = sq[i * 4 + h];
        float trg = sigm(sqi + sk[i * 4 + h] + bsv);
        float ga[3];
#pragma unroll
        for (int q = 0; q < 3; q++) {
            int jj = gsrc[g * 4 + 1 + q];
            ga[q] = sigm(sqi + sk[jj * 4 + h] + bsv);
        }
        float ss = (ga[0] + ga[1] + ga[2]) * (1.f / 3.f);
        float mx = fmaxf(ss, trg);
        float e0 = __expf(ss - mx), e1 = __expf(trg - mx);
        float inv = 1.f / (e0 + e1);
        float tw0 = e0 * inv, tw1 = e1 * inv;
        float mg = fmaxf(ga[0], fmaxf(ga[1], ga[2]));
        float w0 = __expf(ga[0] - mg), w1 = __expf(ga[1] - mg), w2 = __expf(ga[2] - mg);
        float wi = tw0 * 3.f / (w0 + w1 + w2);
        storeF(out, g * 16 + 0 + h,  tw1,     f);
        storeF(out, g * 16 + 4 + h,  w0 * wi, f);
        storeF(out, g * 16 + 8 + h,  w1 * wi, f);
        storeF(out, g * 16 + 12 + h, w2 * wi, f);
    }
}

extern "C" void kernel_launch(void* const* d_in, const int* in_sizes, int n_in,
                              void* d_out, int out_size, void* d_ws, size_t ws_size,
                              hipStream_t stream) {
    // -------- inputs --------
    const void* x        = d_in[0];
    const int*  ei       = (const int*)d_in[1];
    const void* a2s_msg  = d_in[2];
    const void* a2s_hid  = d_in[3];
    const void* s2a_msg  = d_in[4];
    const void* s2a_hid  = d_in[5];
    const void* prefix   = d_in[6];
    const int*  fidx     = (const int*)d_in[7];
    const int*  gidx     = (const int*)d_in[8];
    const int*  gsrc     = (const int*)d_in[9];
    const void* g1_Wih   = d_in[10];
    const void* g1_Whh   = d_in[11];
    const void* g1_bih   = d_in[12];
    const void* g1_bhh   = d_in[13];
    const void* g2_Wih   = d_in[14];
    const void* g2_Whh   = d_in[15];
    const void* g2_bih   = d_in[16];
    const void* g2_bhh   = d_in[17];
    const void* W1  = d_in[18];
    const void* as1 = d_in[19];
    const void* ad1 = d_in[20];
    const void* b1  = d_in[21];
    const void* W2  = d_in[22];
    const void* as2 = d_in[23];
    const void* ad2 = d_in[24];
    const void* b2  = d_in[25];
    const void* W3  = d_in[26];
    const void* as3 = d_in[27];
    const void* ad3 = d_in[28];
    const void* b3  = d_in[29];
    const void* W4  = d_in[30];
    const void* as4 = d_in[31];
    const void* ad4 = d_in[32];
    const void* b4  = d_in[33];
    const void* Wq  = d_in[34];
    const void* Wk  = d_in[35];
    const void* Ws  = d_in[36];
    const void* bs  = d_in[37];

    const int* src_e = ei;
    const int* dst_e = ei + EED;

    // -------- workspace layout --------
    char* wp = (char*)d_ws;
    auto alloc = [&](size_t bytes) {
        char* p = wp;
        wp += (bytes + 255) & ~(size_t)255;
        return p;
    };
    int*   csr   = (int*)alloc((size_t)ETOT * 4);              // 8.8 MB
    int*   offs  = (int*)alloc((size_t)(NND + 1) * 4);         // 0.8 MB
    int*   gtail = (int*)alloc((size_t)NB * 4);
    int*   dflag = (int*)alloc(256);
    float* asb   = (float*)alloc((size_t)NND * 4 * 4);         // 3.2 MB
    float* adb   = (float*)alloc((size_t)NND * 4 * 4);         // 3.2 MB
    float* pool  = (float*)alloc((size_t)MMD * 32 * 4);
    bf16*  bufA  = (bf16*)alloc((size_t)NND * 32 * 2);         // 12.8 MB
    bf16*  bufB  = (bf16*)alloc((size_t)NND * 32 * 2);         // 12.8 MB
    // staging for CSR build reuses bufB (12.54 MB, consumed before feat1)
    unsigned int* stage = (unsigned int*)bufB;

    // -------- dtype detection + gtail zero --------
    detect_kernel<<<1, 64, 0, stream>>>(x, dflag, gtail);

    // -------- assemble xx0 into bufA (stride 16) --------
    assemble_kernel<<<(NXD * 19 + 255) / 256, 256, 0, stream>>>(x, prefix, bufA, dflag);
    gru2_kernel<<<392, 256, 0, stream>>>(a2s_msg, a2s_hid, g1_Wih, g1_Whh, g1_bih, g1_bhh,
                                         s2a_msg, s2a_hid, g2_Wih, g2_Whh, g2_bih, g2_bhh,
                                         d_out, bufA, dflag);

    // -------- CSR build: bin -> build --------
    bin_kernel<<<(ETOT + TILE - 1) / TILE, 256, 0, stream>>>(src_e, dst_e, gtail, stage);
    build_kernel<<<NB, 256, 0, stream>>>(stage, gtail, offs, csr);

    // -------- GAT layers 1..3 (ping-pong bufA <-> bufB) --------
    const int nblk_feat = NND / 8;   // 25000
    const int nblk_agg  = NND / 64;  // 3125
    feat_kernel<16><<<nblk_feat, 256, 0, stream>>>(bufA, W1, as1, ad1, bufB, asb, adb, dflag);
    agg_kernel<<<nblk_agg, 256, 0, stream>>>(bufB, asb, adb, offs, csr, b1, bufA, dflag);
    feat_kernel<32><<<nblk_feat, 256, 0, stream>>>(bufA, W2, as2, ad2, bufB, asb, adb, dflag);
    agg_kernel<<<nblk_agg, 256, 0, stream>>>(bufB, asb, adb, offs, csr, b2, bufA, dflag);
    feat_kernel<32><<<nblk_feat, 256, 0, stream>>>(bufA, W3, as3, ad3, bufB, asb, adb, dflag);
    agg_kernel<<<nblk_agg, 256, 0, stream>>>(bufB, asb, adb, offs, csr, b3, bufA, dflag);

    // -------- layer 4 only at the 1024 pooled nodes --------
    layer4_kernel<<<MMD / 4, 256, 0, stream>>>(bufA, W4, as4, ad4, b4, fidx, offs, csr, pool, dflag);

    // -------- fused final scoring --------
    tail_kernel<<<1, 256, 0, stream>>>(Wq, Wk, Ws, bs, gidx, gsrc, pool, d_out, dflag);
}

// Round 9
// 527.757 us; speedup vs baseline: 1.2452x; 1.2452x over previous
//
#include <hip/hip_runtime.h>
#include <hip/hip_bf16.h>

#define NXD   100000
#define AROWS 50000
#define NND   200000   // total nodes
#define EED   2000000  // given edges
#define ETOT  2200000  // + self loops
#define GHD   13
#define MMD   1024

#define OUT_H1 16384
#define OUT_H2 (16384 + AROWS * GHD)

#define NB    196      // buckets for CSR build (1024 nodes each)
#define BSH   10
#define CAP   16000    // staging capacity per bucket (mean 11264)
#define TILE  4096     // edges per bin-pass block (538 blocks)

typedef __hip_bfloat16 bf16;
typedef unsigned int uvec4 __attribute__((ext_vector_type(4)));

__device__ __forceinline__ float bf2f(bf16 v) { return __bfloat162float(v); }
__device__ __forceinline__ float sigm(float x) { return 1.f / (1.f + __expf(-x)); }
__device__ __forceinline__ float tanhfast(float x) {
    x = fminf(15.f, fmaxf(-15.f, x));
    float t = __expf(-2.f * x);
    return (1.f - t) / (1.f + t);
}
__device__ __forceinline__ float lrelu(float x, float s) { return x > 0.f ? x : s * x; }

__device__ __forceinline__ unsigned short f2bf_bits(float v) {
    bf16 b = __float2bfloat16(v);
    return *reinterpret_cast<unsigned short*>(&b);
}
__device__ __forceinline__ float bflo(unsigned int u) { return __uint_as_float((u & 0xFFFFu) << 16); }
__device__ __forceinline__ float bfhi(unsigned int u) { return __uint_as_float(u & 0xFFFF0000u); }

// Generic input load / output store: f32 flag picks fp32 vs bf16 interpretation.
__device__ __forceinline__ float loadF(const void* p, size_t i, int f32) {
    return f32 ? ((const float*)p)[i] : bf2f(((const bf16*)p)[i]);
}
__device__ __forceinline__ void storeF(void* p, size_t i, float v, int f32) {
    if (f32) ((float*)p)[i] = v;
    else ((bf16*)p)[i] = __float2bfloat16(v);
}

// ---------------- dtype detection + gtail zero ----------------
__global__ void detect_kernel(const void* __restrict__ xp, int* __restrict__ flag,
                              int* __restrict__ gtail) {
    int lane = threadIdx.x;  // 64
    const unsigned short* u = (const unsigned short*)xp;
    unsigned short b = u[lane * 2];
    int e = (b >> 7) & 0xFF;
    int viol = (e == 0xFF) || (e < 64) || (e > 190);
    unsigned long long mask = __ballot(viol != 0);
    if (lane == 0) flag[0] = (__popcll(mask) > 8) ? 1 : 0;  // 1 => fp32 inputs
    for (int i = lane; i < NB; i += 64) gtail[i] = 0;
}

// ---------------- x rows + prefix columns into bufA ----------------
__global__ void assemble_kernel(const void* __restrict__ x, const void* __restrict__ prefix,
                                bf16* __restrict__ bufA, const int* __restrict__ flag) {
    int f = *flag;
    int t = blockIdx.x * 256 + threadIdx.x;
    if (t < NXD * 16) {
        bufA[t] = __float2bfloat16(loadF(x, t, f));
    } else {
        int u = t - NXD * 16;
        if (u < NXD * 3) {
            int r = u / 3, c = u - r * 3;
            bufA[(size_t)(NXD + r) * 16 + c] = __float2bfloat16(loadF(prefix, u, f));
        }
    }
}

// ---------------- both GRUs in one kernel (50000 rows each, in=1, hidden=13) ----------------
__global__ void gru2_kernel(const void* __restrict__ msg1, const void* __restrict__ hid1,
                            const void* __restrict__ Wih1, const void* __restrict__ Whh1,
                            const void* __restrict__ bih1, const void* __restrict__ bhh1,
                            const void* __restrict__ msg2, const void* __restrict__ hid2,
                            const void* __restrict__ Wih2, const void* __restrict__ Whh2,
                            const void* __restrict__ bih2, const void* __restrict__ bhh2,
                            void* __restrict__ dout, bf16* __restrict__ xxA,
                            const int* __restrict__ flag) {
    int f = *flag;
    int which = blockIdx.x >= 196;
    const void* msg = which ? msg2 : msg1;
    const void* hid = which ? hid2 : hid1;
    const void* Wih = which ? Wih2 : Wih1;
    const void* Whh = which ? Whh2 : Whh1;
    const void* bih = which ? bih2 : bih1;
    const void* bhh = which ? bhh2 : bhh1;
    size_t houtbase = which ? (size_t)OUT_H2 : (size_t)OUT_H1;
    int rowbase = which ? AROWS : 0;
    int blk = blockIdx.x - (which ? 196 : 0);
    __shared__ float WhhL[39 * 13], WihL[39], bihL[39], bhhL[39];
    int tid = threadIdx.x;
    for (int i = tid; i < 39 * 13; i += 256) WhhL[i] = loadF(Whh, i, f);
    if (tid < 39) { WihL[tid] = loadF(Wih, tid, f); bihL[tid] = loadF(bih, tid, f); bhhL[tid] = loadF(bhh, tid, f); }
    __syncthreads();
    int n = blk * 256 + tid;
    if (n >= AROWS) return;
    float x = loadF(msg, n, f);
    float h[GHD];
#pragma unroll
    for (int k = 0; k < GHD; k++) h[k] = loadF(hid, n * GHD + k, f);
#pragma unroll
    for (int k = 0; k < GHD; k++) {
        float gir = fmaf(x, WihL[k],      bihL[k]);
        float giz = fmaf(x, WihL[13 + k], bihL[13 + k]);
        float gin = fmaf(x, WihL[26 + k], bihL[26 + k]);
        float ghr = bhhL[k], ghz = bhhL[13 + k], ghn = bhhL[26 + k];
#pragma unroll
        for (int q = 0; q < GHD; q++) {
            ghr = fmaf(h[q], WhhL[k * 13 + q],        ghr);
            ghz = fmaf(h[q], WhhL[(13 + k) * 13 + q], ghz);
            ghn = fmaf(h[q], WhhL[(26 + k) * 13 + q], ghn);
        }
        float r = sigm(gir + ghr);
        float z = sigm(giz + ghz);
        float nn = tanhfast(gin + r * ghn);
        float o = (1.f - z) * nn + z * h[k];
        storeF(dout, houtbase + (size_t)n * GHD + k, o, f);
        xxA[(size_t)(NXD + rowbase + n) * 16 + 3 + k] = __float2bfloat16(o);
    }
}

// ---------------- CSR build: bin pass ----------------
__global__ void bin_kernel(const int* __restrict__ src_e, const int* __restrict__ dst_e,
                           int* __restrict__ gtail, unsigned int* __restrict__ stage) {
    __shared__ int hist[NB];
    __shared__ int base[NB];
    __shared__ int cur[NB];
    int tid = threadIdx.x;
    for (int i = tid; i < NB; i += 256) hist[i] = 0;
    __syncthreads();
    int t0 = blockIdx.x * TILE;
    int tend = t0 + TILE; if (tend > ETOT) tend = ETOT;
    for (int t = t0 + tid; t < tend; t += 256) {
        int d = (t < EED) ? dst_e[t] : (t - EED);
        atomicAdd(&hist[d >> BSH], 1);
    }
    __syncthreads();
    for (int i = tid; i < NB; i += 256) {
        int c = hist[i];
        base[i] = (c > 0) ? atomicAdd(&gtail[i], c) : 0;
        cur[i] = 0;
    }
    __syncthreads();
    for (int t = t0 + tid; t < tend; t += 256) {
        int s, d;
        if (t < EED) { s = src_e[t]; d = dst_e[t]; } else { s = d = t - EED; }
        int b = d >> BSH;
        int p = base[b] + atomicAdd(&cur[b], 1);
        if (p < CAP)
            stage[(size_t)b * CAP + p] = ((unsigned int)(d & 1023) << 18) | (unsigned int)s;
    }
}

// ---------------- CSR build: per-bucket placement (ebase computed in-kernel) ----------------
__global__ void build_kernel(const unsigned int* __restrict__ stage,
                             const int* __restrict__ gtail,
                             int* __restrict__ offs, int* __restrict__ csr) {
    __shared__ int cnt[1024];
    __shared__ int loc[1024];
    __shared__ int cur[1024];
    __shared__ int lds[256];
    int b = blockIdx.x;
    int tid = threadIdx.x;
    int v = (tid < NB) ? gtail[tid] : 0;
    lds[tid] = v; __syncthreads();
    for (int off = 1; off < 256; off <<= 1) {
        int t2 = (tid >= off) ? lds[tid - off] : 0;
        __syncthreads();
        lds[tid] += t2;
        __syncthreads();
    }
    __shared__ int ebs;
    if (tid == b) ebs = lds[tid] - v;
    __syncthreads();
    int eb = ebs;
    int nE = gtail[b]; if (nE > CAP) nE = CAP;
    const unsigned int* st = stage + (size_t)b * CAP;
    for (int i = tid; i < 1024; i += 256) cnt[i] = 0;
    __syncthreads();
    for (int i = tid; i < nE; i += 256)
        atomicAdd(&cnt[st[i] >> 18], 1);
    __syncthreads();
    int c0 = cnt[tid * 4], c1 = cnt[tid * 4 + 1], c2 = cnt[tid * 4 + 2], c3 = cnt[tid * 4 + 3];
    int s = c0 + c1 + c2 + c3;
    lds[tid] = s; __syncthreads();
    for (int off = 1; off < 256; off <<= 1) {
        int t2 = (tid >= off) ? lds[tid - off] : 0;
        __syncthreads();
        lds[tid] += t2;
        __syncthreads();
    }
    int run = lds[tid] - s;
    loc[tid * 4]     = run;
    loc[tid * 4 + 1] = run + c0;
    loc[tid * 4 + 2] = run + c0 + c1;
    loc[tid * 4 + 3] = run + c0 + c1 + c2;
    __syncthreads();
    int nodebase = b << BSH;
    for (int i = tid; i < 1024; i += 256) {
        cur[i] = loc[i];
        int n = nodebase + i;
        if (n < NND) offs[n] = eb + loc[i];
    }
    if (b == 0 && tid == 0) offs[NND] = ETOT;
    __syncthreads();
    for (int i = tid; i < nE; i += 256) {
        unsigned int e = st[i];
        int dl = e >> 18;
        int src = e & 0x3FFFF;
        int p = atomicAdd(&cur[dl], 1);
        csr[eb + p] = src;
    }
}

// ---------------- per-layer features: h = xx@W only ----------------
template <int K>
__global__ void feat_kernel(const bf16* __restrict__ xx,
                            const void* __restrict__ W,
                            bf16* __restrict__ hbuf, const int* __restrict__ flag) {
    int f = *flag;
    __shared__ float Wl[K * 32];
    int tid = threadIdx.x;
    for (int i = tid; i < K * 32; i += 256) Wl[i] = loadF(W, i, f);
    __syncthreads();
    int n = blockIdx.x * 8 + (tid >> 5);
    int j = tid & 31;
    const uvec4* xr4 = (const uvec4*)(xx + (size_t)n * K);
    float v = 0.f;
#pragma unroll
    for (int q = 0; q < K / 8; q++) {
        uvec4 u = xr4[q];
        v = fmaf(bflo(u.x), Wl[(q * 8 + 0) * 32 + j], v);
        v = fmaf(bfhi(u.x), Wl[(q * 8 + 1) * 32 + j], v);
        v = fmaf(bflo(u.y), Wl[(q * 8 + 2) * 32 + j], v);
        v = fmaf(bfhi(u.y), Wl[(q * 8 + 3) * 32 + j], v);
        v = fmaf(bflo(u.z), Wl[(q * 8 + 4) * 32 + j], v);
        v = fmaf(bfhi(u.z), Wl[(q * 8 + 5) * 32 + j], v);
        v = fmaf(bflo(u.w), Wl[(q * 8 + 6) * 32 + j], v);
        v = fmaf(bfhi(u.w), Wl[(q * 8 + 7) * 32 + j], v);
    }
    hbuf[(size_t)n * 32 + j] = __float2bfloat16(v);
}

// ---------------- aggregation (layers 1-3): segment softmax ----------------
// 4 lanes per node (lane == head), 8 channels/lane via 16B loads.
// as/ad computed IN-REGISTER from the h row (no asb/adb gather).
// Plain exp (no max-tracking): |e| << 50 by construction; clamp guards overflow.
// Depth-2 pipeline on csr->h chain; NT only on the streaming output store.
__global__ void agg_kernel(const bf16* __restrict__ hbuf, const int* __restrict__ offs,
                           const int* __restrict__ csr, const void* __restrict__ asrc,
                           const void* __restrict__ adst, const void* __restrict__ bias,
                           bf16* __restrict__ xxout, const int* __restrict__ flag) {
    int f = *flag;
    __shared__ float bl[32], asl[32], adl[32];
    int tid = threadIdx.x;
    if (tid < 32) {
        bl[tid]  = loadF(bias, tid, f);
        asl[tid] = loadF(asrc, tid, f);
        adl[tid] = loadF(adst, tid, f);
    }
    __syncthreads();
    int n = blockIdx.x * 64 + (tid >> 2);
    int j = tid & 3;                 // head j, channels 8j..8j+7
    int cb = 8 * j;
    float A0 = asl[cb], A1 = asl[cb + 1], A2 = asl[cb + 2], A3 = asl[cb + 3];
    float A4 = asl[cb + 4], A5 = asl[cb + 5], A6 = asl[cb + 6], A7 = asl[cb + 7];
    // ad(dst) from own row (sequential load)
    uvec4 hd = *(const uvec4*)(hbuf + (size_t)n * 32 + cb);
    float adv;
    {
        float s = bflo(hd.x) * adl[cb]     + bfhi(hd.x) * adl[cb + 1]
                + bflo(hd.y) * adl[cb + 2] + bfhi(hd.y) * adl[cb + 3]
                + bflo(hd.z) * adl[cb + 4] + bfhi(hd.z) * adl[cb + 5]
                + bflo(hd.w) * adl[cb + 6] + bfhi(hd.w) * adl[cb + 7];
        adv = s;
    }
    int beg = offs[n], end = offs[n + 1];
    int cnt = end - beg;
    const int* cp = csr + beg;
    // preamble (self-loop guarantees cnt >= 1)
    int s0 = cp[0];
    uvec4 h0 = *(const uvec4*)(hbuf + (size_t)s0 * 32 + cb);
    uvec4 h1 = h0;
    if (cnt > 1) {
        int s1 = cp[1];
        h1 = *(const uvec4*)(hbuf + (size_t)s1 * 32 + cb);
    }
    float den = 0.f;
    float a0 = 0.f, a1 = 0.f, a2 = 0.f, a3 = 0.f, a4 = 0.f, a5 = 0.f, a6 = 0.f, a7 = 0.f;
    for (int i = 0; i < cnt; i++) {
        uvec4 hn = (uvec4)(0u);
        if (i + 2 < cnt) {
            int sn = cp[i + 2];
            hn = *(const uvec4*)(hbuf + (size_t)sn * 32 + cb);
        }
        float v0 = bflo(h0.x), v1 = bfhi(h0.x), v2 = bflo(h0.y), v3 = bfhi(h0.y);
        float v4 = bflo(h0.z), v5 = bfhi(h0.z), v6 = bflo(h0.w), v7 = bfhi(h0.w);
        float as = v0 * A0 + v1 * A1 + v2 * A2 + v3 * A3
                 + v4 * A4 + v5 * A5 + v6 * A6 + v7 * A7;
        float e = as + adv;
        e = e > 0.f ? e : 0.2f * e;
        e = fminf(50.f, fmaxf(-50.f, e));
        float w = __expf(e);
        den += w;
        a0 = fmaf(w, v0, a0); a1 = fmaf(w, v1, a1);
        a2 = fmaf(w, v2, a2); a3 = fmaf(w, v3, a3);
        a4 = fmaf(w, v4, a4); a5 = fmaf(w, v5, a5);
        a6 = fmaf(w, v6, a6); a7 = fmaf(w, v7, a7);
        h0 = h1; h1 = hn;
    }
    float inv = 1.f / den;
    float o0 = lrelu(fmaf(a0, inv, bl[cb + 0]), 0.01f);
    float o1 = lrelu(fmaf(a1, inv, bl[cb + 1]), 0.01f);
    float o2 = lrelu(fmaf(a2, inv, bl[cb + 2]), 0.01f);
    float o3 = lrelu(fmaf(a3, inv, bl[cb + 3]), 0.01f);
    float o4 = lrelu(fmaf(a4, inv, bl[cb + 4]), 0.01f);
    float o5 = lrelu(fmaf(a5, inv, bl[cb + 5]), 0.01f);
    float o6 = lrelu(fmaf(a6, inv, bl[cb + 6]), 0.01f);
    float o7 = lrelu(fmaf(a7, inv, bl[cb + 7]), 0.01f);
    uvec4 p;
    p.x = ((unsigned int)f2bf_bits(o1) << 16) | f2bf_bits(o0);
    p.y = ((unsigned int)f2bf_bits(o3) << 16) | f2bf_bits(o2);
    p.z = ((unsigned int)f2bf_bits(o5) << 16) | f2bf_bits(o4);
    p.w = ((unsigned int)f2bf_bits(o7) << 16) | f2bf_bits(o6);
    __builtin_nontemporal_store(p, (uvec4*)(xxout + (size_t)n * 32 + cb));
}

// ---------------- layer 4: only at the 1024 function nodes ----------------
__global__ void layer4_kernel(const bf16* __restrict__ xx,
                              const void* __restrict__ W4,
                              const void* __restrict__ asrc,
                              const void* __restrict__ adst,
                              const void* __restrict__ b4,
                              const int* __restrict__ fidx, const int* __restrict__ offs,
                              const int* __restrict__ csr, float* __restrict__ pool,
                              const int* __restrict__ flag) {
    int f = *flag;
    __shared__ float Wl[32 * 128];
    __shared__ float asl[128], adl[128], bl[32];
    int tid = threadIdx.x;
    for (int i = tid; i < 32 * 128; i += 256) Wl[i] = loadF(W4, i, f);
    if (tid < 128) { asl[tid] = loadF(asrc, tid, f); adl[tid] = loadF(adst, tid, f); }
    if (tid < 32) bl[tid] = loadF(b4, tid, f);
    __syncthreads();
    int wave = tid >> 6, lane = tid & 63;
    int g = blockIdx.x * 4 + wave;
    int d = fidx[g];
    int c = lane & 31;
    int h0 = lane >> 5;
    int h1 = h0 + 2;
    const bf16* xd = xx + (size_t)d * 32;
    float v0 = 0.f, v1 = 0.f;
#pragma unroll
    for (int k = 0; k < 32; k++) {
        float xv = bf2f(xd[k]);
        v0 = fmaf(xv, Wl[k * 128 + lane], v0);
        v1 = fmaf(xv, Wl[k * 128 + lane + 64], v1);
    }
    float ad0 = v0 * adl[h0 * 32 + c];
    float ad1 = v1 * adl[h1 * 32 + c];
#pragma unroll
    for (int mk = 1; mk < 32; mk <<= 1) { ad0 += __shfl_xor(ad0, mk); ad1 += __shfl_xor(ad1, mk); }
    float m0 = -1e30f, den0 = 0.f, acc0 = 0.f;
    float m1 = -1e30f, den1 = 0.f, acc1 = 0.f;
    int beg = offs[d], end = offs[d + 1];
    for (int i = beg; i < end; i++) {
        int s = csr[i];
        const bf16* xs = xx + (size_t)s * 32;
        float s0 = 0.f, s1 = 0.f;
#pragma unroll
        for (int k = 0; k < 32; k++) {
            float xv = bf2f(xs[k]);
            s0 = fmaf(xv, Wl[k * 128 + lane], s0);
            s1 = fmaf(xv, Wl[k * 128 + lane + 64], s1);
        }
        float as0 = s0 * asl[h0 * 32 + c];
        float as1 = s1 * asl[h1 * 32 + c];
#pragma unroll
        for (int mk = 1; mk < 32; mk <<= 1) { as0 += __shfl_xor(as0, mk); as1 += __shfl_xor(as1, mk); }
        float e0 = lrelu(as0 + ad0, 0.2f);
        float e1 = lrelu(as1 + ad1, 0.2f);
        if (e0 <= m0) { float w = __expf(e0 - m0); den0 += w; acc0 = fmaf(w, s0, acc0); }
        else { float sc = __expf(m0 - e0); den0 = fmaf(den0, sc, 1.f); acc0 = fmaf(acc0, sc, s0); m0 = e0; }
        if (e1 <= m1) { float w = __expf(e1 - m1); den1 += w; acc1 = fmaf(w, s1, acc1); }
        else { float sc = __expf(m1 - e1); den1 = fmaf(den1, sc, 1.f); acc1 = fmaf(acc1, sc, s1); m1 = e1; }
    }
    float t = acc0 / den0 + acc1 / den1;
    t += __shfl_xor(t, 32);
    if (lane < 32) {
        float o = t * 0.25f + bl[c];
        pool[g * 32 + c] = lrelu(o, 0.01f);
    }
}

// ---------------- fused final scoring: vq/vk + sq/sk + weights (one block) ----------------
__global__ void tail_kernel(const void* __restrict__ Wq, const void* __restrict__ Wk,
                            const void* __restrict__ Ws, const void* __restrict__ bs,
                            const int* __restrict__ gidx, const int* __restrict__ gsrc,
                            const float* __restrict__ pool, void* __restrict__ out,
                            const int* __restrict__ flag) {
    int f = *flag;
    __shared__ float vq[128], vk[128];
    __shared__ float sq[4096], sk[4096];
    int tid = threadIdx.x;  // 256
    {
        int which = tid >> 7;
        int i = tid & 127;
        int h = i >> 5, dd = i & 31;
        const void* Wm = which ? Wk : Wq;
        float sum = 0.f;
#pragma unroll
        for (int o = 0; o < 32; o++)
            sum = fmaf(loadF(Wm, (h * 32 + dd) * 32 + o, f), loadF(Ws, h * 64 + which * 32 + o, f), sum);
        (which ? vk : vq)[i] = sum;
    }
    __syncthreads();
    for (int idx = tid; idx < 8192; idx += 256) {
        int which = idx >> 12;
        int i = idx & 4095;
        int g = i >> 2, h = i & 3;
        const float* V = which ? vk : vq;
        float s = 0.f;
#pragma unroll
        for (int dd = 0; dd < 32; dd++) s = fmaf(pool[g * 32 + dd], V[h * 32 + dd], s);
        (which ? sk : sq)[i] = s;
    }
    __syncthreads();
    for (int t = tid; t < 4096; t += 256) {
        int g = t >> 2, h = t & 3;
        int i = gidx[g];
        float bsv = loadF(bs, h, f);
        float sqi = sq[i * 4 + h];
        float trg = sigm(sqi + sk[i * 4 + h] + bsv);
        float ga[3];
#pragma unroll
        for (int q = 0; q < 3; q++) {
            int jj = gsrc[g * 4 + 1 + q];
            ga[q] = sigm(sqi + sk[jj * 4 + h] + bsv);
        }
        float ss = (ga[0] + ga[1] + ga[2]) * (1.f / 3.f);
        float mx = fmaxf(ss, trg);
        float e0 = __expf(ss - mx), e1 = __expf(trg - mx);
        float inv = 1.f / (e0 + e1);
        float tw0 = e0 * inv, tw1 = e1 * inv;
        float mg = fmaxf(ga[0], fmaxf(ga[1], ga[2]));
        float w0 = __expf(ga[0] - mg), w1 = __expf(ga[1] - mg), w2 = __expf(ga[2] - mg);
        float wi = tw0 * 3.f / (w0 + w1 + w2);
        storeF(out, g * 16 + 0 + h,  tw1,     f);
        storeF(out, g * 16 + 4 + h,  w0 * wi, f);
        storeF(out, g * 16 + 8 + h,  w1 * wi, f);
        storeF(out, g * 16 + 12 + h, w2 * wi, f);
    }
}

extern "C" void kernel_launch(void* const* d_in, const int* in_sizes, int n_in,
                              void* d_out, int out_size, void* d_ws, size_t ws_size,
                              hipStream_t stream) {
    // -------- inputs --------
    const void* x        = d_in[0];
    const int*  ei       = (const int*)d_in[1];
    const void* a2s_msg  = d_in[2];
    const void* a2s_hid  = d_in[3];
    const void* s2a_msg  = d_in[4];
    const void* s2a_hid  = d_in[5];
    const void* prefix   = d_in[6];
    const int*  fidx     = (const int*)d_in[7];
    const int*  gidx     = (const int*)d_in[8];
    const int*  gsrc     = (const int*)d_in[9];
    const void* g1_Wih   = d_in[10];
    const void* g1_Whh   = d_in[11];
    const void* g1_bih   = d_in[12];
    const void* g1_bhh   = d_in[13];
    const void* g2_Wih   = d_in[14];
    const void* g2_Whh   = d_in[15];
    const void* g2_bih   = d_in[16];
    const void* g2_bhh   = d_in[17];
    const void* W1  = d_in[18];
    const void* as1 = d_in[19];
    const void* ad1 = d_in[20];
    const void* b1  = d_in[21];
    const void* W2  = d_in[22];
    const void* as2 = d_in[23];
    const void* ad2 = d_in[24];
    const void* b2  = d_in[25];
    const void* W3  = d_in[26];
    const void* as3 = d_in[27];
    const void* ad3 = d_in[28];
    const void* b3  = d_in[29];
    const void* W4  = d_in[30];
    const void* as4 = d_in[31];
    const void* ad4 = d_in[32];
    const void* b4  = d_in[33];
    const void* Wq  = d_in[34];
    const void* Wk  = d_in[35];
    const void* Ws  = d_in[36];
    const void* bs  = d_in[37];

    const int* src_e = ei;
    const int* dst_e = ei + EED;

    // -------- workspace layout --------
    char* wp = (char*)d_ws;
    auto alloc = [&](size_t bytes) {
        char* p = wp;
        wp += (bytes + 255) & ~(size_t)255;
        return p;
    };
    int*   csr   = (int*)alloc((size_t)ETOT * 4);              // 8.8 MB
    int*   offs  = (int*)alloc((size_t)(NND + 1) * 4);         // 0.8 MB
    int*   gtail = (int*)alloc((size_t)NB * 4);
    int*   dflag = (int*)alloc(256);
    float* pool  = (float*)alloc((size_t)MMD * 32 * 4);
    bf16*  bufA  = (bf16*)alloc((size_t)NND * 32 * 2);         // 12.8 MB
    bf16*  bufB  = (bf16*)alloc((size_t)NND * 32 * 2);         // 12.8 MB
    // staging for CSR build reuses bufB (12.54 MB, consumed before feat1)
    unsigned int* stage = (unsigned int*)bufB;

    // -------- dtype detection + gtail zero --------
    detect_kernel<<<1, 64, 0, stream>>>(x, dflag, gtail);

    // -------- assemble xx0 into bufA (stride 16) --------
    assemble_kernel<<<(NXD * 19 + 255) / 256, 256, 0, stream>>>(x, prefix, bufA, dflag);
    gru2_kernel<<<392, 256, 0, stream>>>(a2s_msg, a2s_hid, g1_Wih, g1_Whh, g1_bih, g1_bhh,
                                         s2a_msg, s2a_hid, g2_Wih, g2_Whh, g2_bih, g2_bhh,
                                         d_out, bufA, dflag);

    // -------- CSR build: bin -> build --------
    bin_kernel<<<(ETOT + TILE - 1) / TILE, 256, 0, stream>>>(src_e, dst_e, gtail, stage);
    build_kernel<<<NB, 256, 0, stream>>>(stage, gtail, offs, csr);

    // -------- GAT layers 1..3 (ping-pong bufA <-> bufB) --------
    const int nblk_feat = NND / 8;   // 25000
    const int nblk_agg  = NND / 64;  // 3125
    feat_kernel<16><<<nblk_feat, 256, 0, stream>>>(bufA, W1, bufB, dflag);
    agg_kernel<<<nblk_agg, 256, 0, stream>>>(bufB, offs, csr, as1, ad1, b1, bufA, dflag);
    feat_kernel<32><<<nblk_feat, 256, 0, stream>>>(bufA, W2, bufB, dflag);
    agg_kernel<<<nblk_agg, 256, 0, stream>>>(bufB, offs, csr, as2, ad2, b2, bufA, dflag);
    feat_kernel<32><<<nblk_feat, 256, 0, stream>>>(bufA, W3, bufB, dflag);
    agg_kernel<<<nblk_agg, 256, 0, stream>>>(bufB, offs, csr, as3, ad3, b3, bufA, dflag);

    // -------- layer 4 only at the 1024 pooled nodes --------
    layer4_kernel<<<MMD / 4, 256, 0, stream>>>(bufA, W4, as4, ad4, b4, fidx, offs, csr, pool, dflag);

    // -------- fused final scoring --------
    tail_kernel<<<1, 256, 0, stream>>>(Wq, Wk, Ws, bs, gidx, gsrc, pool, d_out, dflag);
}

// Round 10
// 490.847 us; speedup vs baseline: 1.3389x; 1.0752x over previous
//
#include <hip/hip_runtime.h>
#include <hip/hip_bf16.h>

#define NXD   100000
#define AROWS 50000
#define NND   200000   // total nodes
#define EED   2000000  // given edges
#define ETOT  2200000  // + self loops
#define GHD   13
#define MMD   1024

#define OUT_H1 16384
#define OUT_H2 (16384 + AROWS * GHD)

#define NB    196      // buckets for CSR build (1024 nodes each)
#define BSH   10
#define CAP   16000    // staging capacity per bucket (mean 11264)
#define TILE  4096     // edges per bin-pass block (538 blocks)

typedef __hip_bfloat16 bf16;
typedef unsigned int uvec4 __attribute__((ext_vector_type(4)));

__device__ __forceinline__ float bf2f(bf16 v) { return __bfloat162float(v); }
__device__ __forceinline__ float sigm(float x) { return 1.f / (1.f + __expf(-x)); }
__device__ __forceinline__ float tanhfast(float x) {
    x = fminf(15.f, fmaxf(-15.f, x));
    float t = __expf(-2.f * x);
    return (1.f - t) / (1.f + t);
}
__device__ __forceinline__ float lrelu(float x, float s) { return x > 0.f ? x : s * x; }

__device__ __forceinline__ unsigned short f2bf_bits(float v) {
    bf16 b = __float2bfloat16(v);
    return *reinterpret_cast<unsigned short*>(&b);
}
__device__ __forceinline__ float bflo(unsigned int u) { return __uint_as_float((u & 0xFFFFu) << 16); }
__device__ __forceinline__ float bfhi(unsigned int u) { return __uint_as_float(u & 0xFFFF0000u); }

// Generic input load / output store: f32 flag picks fp32 vs bf16 interpretation.
__device__ __forceinline__ float loadF(const void* p, size_t i, int f32) {
    return f32 ? ((const float*)p)[i] : bf2f(((const bf16*)p)[i]);
}
__device__ __forceinline__ void storeF(void* p, size_t i, float v, int f32) {
    if (f32) ((float*)p)[i] = v;
    else ((bf16*)p)[i] = __float2bfloat16(v);
}

// ---------------- dtype detection + gtail zero ----------------
__global__ void detect_kernel(const void* __restrict__ xp, int* __restrict__ flag,
                              int* __restrict__ gtail) {
    int lane = threadIdx.x;  // 64
    const unsigned short* u = (const unsigned short*)xp;
    unsigned short b = u[lane * 2];
    int e = (b >> 7) & 0xFF;
    int viol = (e == 0xFF) || (e < 64) || (e > 190);
    unsigned long long mask = __ballot(viol != 0);
    if (lane == 0) flag[0] = (__popcll(mask) > 8) ? 1 : 0;  // 1 => fp32 inputs
    for (int i = lane; i < NB; i += 64) gtail[i] = 0;
}

// ---------------- x rows + prefix columns into bufA ----------------
__global__ void assemble_kernel(const void* __restrict__ x, const void* __restrict__ prefix,
                                bf16* __restrict__ bufA, const int* __restrict__ flag) {
    int f = *flag;
    int t = blockIdx.x * 256 + threadIdx.x;
    if (t < NXD * 16) {
        bufA[t] = __float2bfloat16(loadF(x, t, f));
    } else {
        int u = t - NXD * 16;
        if (u < NXD * 3) {
            int r = u / 3, c = u - r * 3;
            bufA[(size_t)(NXD + r) * 16 + c] = __float2bfloat16(loadF(prefix, u, f));
        }
    }
}

// ---------------- both GRUs in one kernel (50000 rows each, in=1, hidden=13) ----------------
__global__ void gru2_kernel(const void* __restrict__ msg1, const void* __restrict__ hid1,
                            const void* __restrict__ Wih1, const void* __restrict__ Whh1,
                            const void* __restrict__ bih1, const void* __restrict__ bhh1,
                            const void* __restrict__ msg2, const void* __restrict__ hid2,
                            const void* __restrict__ Wih2, const void* __restrict__ Whh2,
                            const void* __restrict__ bih2, const void* __restrict__ bhh2,
                            void* __restrict__ dout, bf16* __restrict__ xxA,
                            const int* __restrict__ flag) {
    int f = *flag;
    int which = blockIdx.x >= 196;
    const void* msg = which ? msg2 : msg1;
    const void* hid = which ? hid2 : hid1;
    const void* Wih = which ? Wih2 : Wih1;
    const void* Whh = which ? Whh2 : Whh1;
    const void* bih = which ? bih2 : bih1;
    const void* bhh = which ? bhh2 : bhh1;
    size_t houtbase = which ? (size_t)OUT_H2 : (size_t)OUT_H1;
    int rowbase = which ? AROWS : 0;
    int blk = blockIdx.x - (which ? 196 : 0);
    __shared__ float WhhL[39 * 13], WihL[39], bihL[39], bhhL[39];
    int tid = threadIdx.x;
    for (int i = tid; i < 39 * 13; i += 256) WhhL[i] = loadF(Whh, i, f);
    if (tid < 39) { WihL[tid] = loadF(Wih, tid, f); bihL[tid] = loadF(bih, tid, f); bhhL[tid] = loadF(bhh, tid, f); }
    __syncthreads();
    int n = blk * 256 + tid;
    if (n >= AROWS) return;
    float x = loadF(msg, n, f);
    float h[GHD];
#pragma unroll
    for (int k = 0; k < GHD; k++) h[k] = loadF(hid, n * GHD + k, f);
#pragma unroll
    for (int k = 0; k < GHD; k++) {
        float gir = fmaf(x, WihL[k],      bihL[k]);
        float giz = fmaf(x, WihL[13 + k], bihL[13 + k]);
        float gin = fmaf(x, WihL[26 + k], bihL[26 + k]);
        float ghr = bhhL[k], ghz = bhhL[13 + k], ghn = bhhL[26 + k];
#pragma unroll
        for (int q = 0; q < GHD; q++) {
            ghr = fmaf(h[q], WhhL[k * 13 + q],        ghr);
            ghz = fmaf(h[q], WhhL[(13 + k) * 13 + q], ghz);
            ghn = fmaf(h[q], WhhL[(26 + k) * 13 + q], ghn);
        }
        float r = sigm(gir + ghr);
        float z = sigm(giz + ghz);
        float nn = tanhfast(gin + r * ghn);
        float o = (1.f - z) * nn + z * h[k];
        storeF(dout, houtbase + (size_t)n * GHD + k, o, f);
        xxA[(size_t)(NXD + rowbase + n) * 16 + 3 + k] = __float2bfloat16(o);
    }
}

// ---------------- CSR build: bin pass ----------------
__global__ void bin_kernel(const int* __restrict__ src_e, const int* __restrict__ dst_e,
                           int* __restrict__ gtail, unsigned int* __restrict__ stage) {
    __shared__ int hist[NB];
    __shared__ int base[NB];
    __shared__ int cur[NB];
    int tid = threadIdx.x;
    for (int i = tid; i < NB; i += 256) hist[i] = 0;
    __syncthreads();
    int t0 = blockIdx.x * TILE;
    int tend = t0 + TILE; if (tend > ETOT) tend = ETOT;
    for (int t = t0 + tid; t < tend; t += 256) {
        int d = (t < EED) ? dst_e[t] : (t - EED);
        atomicAdd(&hist[d >> BSH], 1);
    }
    __syncthreads();
    for (int i = tid; i < NB; i += 256) {
        int c = hist[i];
        base[i] = (c > 0) ? atomicAdd(&gtail[i], c) : 0;
        cur[i] = 0;
    }
    __syncthreads();
    for (int t = t0 + tid; t < tend; t += 256) {
        int s, d;
        if (t < EED) { s = src_e[t]; d = dst_e[t]; } else { s = d = t - EED; }
        int b = d >> BSH;
        int p = base[b] + atomicAdd(&cur[b], 1);
        if (p < CAP)
            stage[(size_t)b * CAP + p] = ((unsigned int)(d & 1023) << 18) | (unsigned int)s;
    }
}

// ---------------- CSR build: per-bucket placement (ebase computed in-kernel) ----------------
__global__ void build_kernel(const unsigned int* __restrict__ stage,
                             const int* __restrict__ gtail,
                             int* __restrict__ offs, int* __restrict__ csr) {
    __shared__ int cnt[1024];
    __shared__ int loc[1024];
    __shared__ int cur[1024];
    __shared__ int lds[256];
    int b = blockIdx.x;
    int tid = threadIdx.x;
    int v = (tid < NB) ? gtail[tid] : 0;
    lds[tid] = v; __syncthreads();
    for (int off = 1; off < 256; off <<= 1) {
        int t2 = (tid >= off) ? lds[tid - off] : 0;
        __syncthreads();
        lds[tid] += t2;
        __syncthreads();
    }
    __shared__ int ebs;
    if (tid == b) ebs = lds[tid] - v;
    __syncthreads();
    int eb = ebs;
    int nE = gtail[b]; if (nE > CAP) nE = CAP;
    const unsigned int* st = stage + (size_t)b * CAP;
    for (int i = tid; i < 1024; i += 256) cnt[i] = 0;
    __syncthreads();
    for (int i = tid; i < nE; i += 256)
        atomicAdd(&cnt[st[i] >> 18], 1);
    __syncthreads();
    int c0 = cnt[tid * 4], c1 = cnt[tid * 4 + 1], c2 = cnt[tid * 4 + 2], c3 = cnt[tid * 4 + 3];
    int s = c0 + c1 + c2 + c3;
    lds[tid] = s; __syncthreads();
    for (int off = 1; off < 256; off <<= 1) {
        int t2 = (tid >= off) ? lds[tid - off] : 0;
        __syncthreads();
        lds[tid] += t2;
        __syncthreads();
    }
    int run = lds[tid] - s;
    loc[tid * 4]     = run;
    loc[tid * 4 + 1] = run + c0;
    loc[tid * 4 + 2] = run + c0 + c1;
    loc[tid * 4 + 3] = run + c0 + c1 + c2;
    __syncthreads();
    int nodebase = b << BSH;
    for (int i = tid; i < 1024; i += 256) {
        cur[i] = loc[i];
        int n = nodebase + i;
        if (n < NND) offs[n] = eb + loc[i];
    }
    if (b == 0 && tid == 0) offs[NND] = ETOT;
    __syncthreads();
    for (int i = tid; i < nE; i += 256) {
        unsigned int e = st[i];
        int dl = e >> 18;
        int src = e & 0x3FFFF;
        int p = atomicAdd(&cur[dl], 1);
        csr[eb + p] = src;
    }
}

// ---------------- per-layer features: h = xx@W only ----------------
template <int K>
__global__ void feat_kernel(const bf16* __restrict__ xx,
                            const void* __restrict__ W,
                            bf16* __restrict__ hbuf, const int* __restrict__ flag) {
    int f = *flag;
    __shared__ float Wl[K * 32];
    int tid = threadIdx.x;
    for (int i = tid; i < K * 32; i += 256) Wl[i] = loadF(W, i, f);
    __syncthreads();
    int n = blockIdx.x * 8 + (tid >> 5);
    int j = tid & 31;
    const uvec4* xr4 = (const uvec4*)(xx + (size_t)n * K);
    float v = 0.f;
#pragma unroll
    for (int q = 0; q < K / 8; q++) {
        uvec4 u = xr4[q];
        v = fmaf(bflo(u.x), Wl[(q * 8 + 0) * 32 + j], v);
        v = fmaf(bfhi(u.x), Wl[(q * 8 + 1) * 32 + j], v);
        v = fmaf(bflo(u.y), Wl[(q * 8 + 2) * 32 + j], v);
        v = fmaf(bfhi(u.y), Wl[(q * 8 + 3) * 32 + j], v);
        v = fmaf(bflo(u.z), Wl[(q * 8 + 4) * 32 + j], v);
        v = fmaf(bfhi(u.z), Wl[(q * 8 + 5) * 32 + j], v);
        v = fmaf(bflo(u.w), Wl[(q * 8 + 6) * 32 + j], v);
        v = fmaf(bfhi(u.w), Wl[(q * 8 + 7) * 32 + j], v);
    }
    hbuf[(size_t)n * 32 + j] = __float2bfloat16(v);
}

// ---------------- aggregation (layers 1-3): segment softmax ----------------
__global__ void agg_kernel(const bf16* __restrict__ hbuf, const int* __restrict__ offs,
                           const int* __restrict__ csr, const void* __restrict__ asrc,
                           const void* __restrict__ adst, const void* __restrict__ bias,
                           bf16* __restrict__ xxout, const int* __restrict__ flag) {
    int f = *flag;
    __shared__ float bl[32], asl[32], adl[32];
    int tid = threadIdx.x;
    if (tid < 32) {
        bl[tid]  = loadF(bias, tid, f);
        asl[tid] = loadF(asrc, tid, f);
        adl[tid] = loadF(adst, tid, f);
    }
    __syncthreads();
    int n = blockIdx.x * 64 + (tid >> 2);
    int j = tid & 3;                 // head j, channels 8j..8j+7
    int cb = 8 * j;
    float A0 = asl[cb], A1 = asl[cb + 1], A2 = asl[cb + 2], A3 = asl[cb + 3];
    float A4 = asl[cb + 4], A5 = asl[cb + 5], A6 = asl[cb + 6], A7 = asl[cb + 7];
    uvec4 hd = *(const uvec4*)(hbuf + (size_t)n * 32 + cb);
    float adv = bflo(hd.x) * adl[cb]     + bfhi(hd.x) * adl[cb + 1]
              + bflo(hd.y) * adl[cb + 2] + bfhi(hd.y) * adl[cb + 3]
              + bflo(hd.z) * adl[cb + 4] + bfhi(hd.z) * adl[cb + 5]
              + bflo(hd.w) * adl[cb + 6] + bfhi(hd.w) * adl[cb + 7];
    int beg = offs[n], end = offs[n + 1];
    int cnt = end - beg;
    const int* cp = csr + beg;
    int s0 = cp[0];
    uvec4 h0 = *(const uvec4*)(hbuf + (size_t)s0 * 32 + cb);
    uvec4 h1 = h0;
    if (cnt > 1) {
        int s1 = cp[1];
        h1 = *(const uvec4*)(hbuf + (size_t)s1 * 32 + cb);
    }
    float den = 0.f;
    float a0 = 0.f, a1 = 0.f, a2 = 0.f, a3 = 0.f, a4 = 0.f, a5 = 0.f, a6 = 0.f, a7 = 0.f;
    for (int i = 0; i < cnt; i++) {
        uvec4 hn = (uvec4)(0u);
        if (i + 2 < cnt) {
            int sn = cp[i + 2];
            hn = *(const uvec4*)(hbuf + (size_t)sn * 32 + cb);
        }
        float v0 = bflo(h0.x), v1 = bfhi(h0.x), v2 = bflo(h0.y), v3 = bfhi(h0.y);
        float v4 = bflo(h0.z), v5 = bfhi(h0.z), v6 = bflo(h0.w), v7 = bfhi(h0.w);
        float as = v0 * A0 + v1 * A1 + v2 * A2 + v3 * A3
                 + v4 * A4 + v5 * A5 + v6 * A6 + v7 * A7;
        float e = as + adv;
        e = e > 0.f ? e : 0.2f * e;
        e = fminf(50.f, fmaxf(-50.f, e));
        float w = __expf(e);
        den += w;
        a0 = fmaf(w, v0, a0); a1 = fmaf(w, v1, a1);
        a2 = fmaf(w, v2, a2); a3 = fmaf(w, v3, a3);
        a4 = fmaf(w, v4, a4); a5 = fmaf(w, v5, a5);
        a6 = fmaf(w, v6, a6); a7 = fmaf(w, v7, a7);
        h0 = h1; h1 = hn;
    }
    float inv = 1.f / den;
    float o0 = lrelu(fmaf(a0, inv, bl[cb + 0]), 0.01f);
    float o1 = lrelu(fmaf(a1, inv, bl[cb + 1]), 0.01f);
    float o2 = lrelu(fmaf(a2, inv, bl[cb + 2]), 0.01f);
    float o3 = lrelu(fmaf(a3, inv, bl[cb + 3]), 0.01f);
    float o4 = lrelu(fmaf(a4, inv, bl[cb + 4]), 0.01f);
    float o5 = lrelu(fmaf(a5, inv, bl[cb + 5]), 0.01f);
    float o6 = lrelu(fmaf(a6, inv, bl[cb + 6]), 0.01f);
    float o7 = lrelu(fmaf(a7, inv, bl[cb + 7]), 0.01f);
    uvec4 p;
    p.x = ((unsigned int)f2bf_bits(o1) << 16) | f2bf_bits(o0);
    p.y = ((unsigned int)f2bf_bits(o3) << 16) | f2bf_bits(o2);
    p.z = ((unsigned int)f2bf_bits(o5) << 16) | f2bf_bits(o4);
    p.w = ((unsigned int)f2bf_bits(o7) << 16) | f2bf_bits(o6);
    __builtin_nontemporal_store(p, (uvec4*)(xxout + (size_t)n * 32 + cb));
}

// ---------------- layer 4: edge-parallel, one block per function node ----------------
// 4 waves split the node's edges; plain-exp softmax (order-independent) so the
// cross-wave merge is a pure LDS atomic add of (acc, den). x rows loaded as 2x16B.
__global__ void layer4_kernel(const bf16* __restrict__ xx,
                              const void* __restrict__ W4,
                              const void* __restrict__ asrc,
                              const void* __restrict__ adst,
                              const void* __restrict__ b4,
                              const int* __restrict__ fidx, const int* __restrict__ offs,
                              const int* __restrict__ csr, float* __restrict__ pool,
                              const int* __restrict__ flag) {
    int f = *flag;
    __shared__ float Wl[32 * 128];
    __shared__ float asl[128], adl[128], bl[32];
    __shared__ float accs[4][32];
    __shared__ float dens[4];
    int tid = threadIdx.x;
    for (int i = tid; i < 32 * 128; i += 256) Wl[i] = loadF(W4, i, f);
    if (tid < 128) { asl[tid] = loadF(asrc, tid, f); adl[tid] = loadF(adst, tid, f); accs[tid >> 5][tid & 31] = 0.f; }
    if (tid < 32) bl[tid] = loadF(b4, tid, f);
    if (tid < 4) dens[tid] = 0.f;
    __syncthreads();
    int g = blockIdx.x;
    int d = fidx[g];
    int wave = tid >> 6, lane = tid & 63;
    int c = lane & 31;
    int h0 = lane >> 5;      // head 0/1
    int h1 = h0 + 2;         // head 2/3
    // ad(dst): all waves compute redundantly (cheap)
    const uvec4* xd4 = (const uvec4*)(xx + (size_t)d * 32);
    uvec4 du0 = xd4[0], du1 = xd4[1];
    float v0 = 0.f, v1 = 0.f;
#pragma unroll
    for (int q = 0; q < 4; q++) {
        unsigned int u = (q < 2) ? ((q & 1) ? du0.y : du0.x) : ((q & 1) ? du0.w : du0.z);
        int k = 2 * q;
        v0 = fmaf(bflo(u), Wl[k * 128 + lane], v0);       v0 = fmaf(bfhi(u), Wl[(k + 1) * 128 + lane], v0);
        v1 = fmaf(bflo(u), Wl[k * 128 + lane + 64], v1);  v1 = fmaf(bfhi(u), Wl[(k + 1) * 128 + lane + 64], v1);
    }
#pragma unroll
    for (int q = 0; q < 4; q++) {
        unsigned int u = (q < 2) ? ((q & 1) ? du1.y : du1.x) : ((q & 1) ? du1.w : du1.z);
        int k = 8 + 2 * q;
        v0 = fmaf(bflo(u), Wl[k * 128 + lane], v0);       v0 = fmaf(bfhi(u), Wl[(k + 1) * 128 + lane], v0);
        v1 = fmaf(bflo(u), Wl[k * 128 + lane + 64], v1);  v1 = fmaf(bfhi(u), Wl[(k + 1) * 128 + lane + 64], v1);
    }
    // NOTE: rows are 32 channels = 8 uints; split into two uvec4 (du0: k=0..15, du1: k=16..31)
    // The loops above cover k=0..15; redo properly for k=16..31 below via a second pass.
    float ad0 = v0 * adl[h0 * 32 + c];
    float ad1 = v1 * adl[h1 * 32 + c];
#pragma unroll
    for (int mk = 1; mk < 32; mk <<= 1) { ad0 += __shfl_xor(ad0, mk); ad1 += __shfl_xor(ad1, mk); }
    int beg = offs[d], end = offs[d + 1];
    float den0 = 0.f, den1 = 0.f, acc0 = 0.f, acc1 = 0.f;
    for (int i = beg + wave; i < end; i += 4) {
        int s = csr[i];
        const uvec4* xs4 = (const uvec4*)(xx + (size_t)s * 32);
        uvec4 su0 = xs4[0], su1 = xs4[1];
        float s0 = 0.f, s1 = 0.f;
        unsigned int us[8] = {su0.x, su0.y, su0.z, su0.w, su1.x, su1.y, su1.z, su1.w};
#pragma unroll
        for (int q = 0; q < 8; q++) {
            unsigned int u = us[q];
            int k = 2 * q;
            s0 = fmaf(bflo(u), Wl[k * 128 + lane], s0);       s0 = fmaf(bfhi(u), Wl[(k + 1) * 128 + lane], s0);
            s1 = fmaf(bflo(u), Wl[k * 128 + lane + 64], s1);  s1 = fmaf(bfhi(u), Wl[(k + 1) * 128 + lane + 64], s1);
        }
        float as0 = s0 * asl[h0 * 32 + c];
        float as1 = s1 * asl[h1 * 32 + c];
#pragma unroll
        for (int mk = 1; mk < 32; mk <<= 1) { as0 += __shfl_xor(as0, mk); as1 += __shfl_xor(as1, mk); }
        float e0 = lrelu(as0 + ad0, 0.2f);
        float e1 = lrelu(as1 + ad1, 0.2f);
        e0 = fminf(50.f, fmaxf(-50.f, e0));
        e1 = fminf(50.f, fmaxf(-50.f, e1));
        float w0 = __expf(e0), w1 = __expf(e1);
        den0 += w0; acc0 = fmaf(w0, s0, acc0);
        den1 += w1; acc1 = fmaf(w1, s1, acc1);
    }
    atomicAdd(&accs[h0][c], acc0);
    atomicAdd(&accs[h1][c], acc1);
    if (c == 0) { atomicAdd(&dens[h0], den0); atomicAdd(&dens[h1], den1); }
    __syncthreads();
    if (tid < 32) {
        float t = accs[0][tid] / dens[0] + accs[1][tid] / dens[1]
                + accs[2][tid] / dens[2] + accs[3][tid] / dens[3];
        float o = t * 0.25f + bl[tid];
        pool[g * 32 + tid] = lrelu(o, 0.01f);
    }
}

// ---------------- fused final scoring: vq/vk + sq/sk + weights (one block) ----------------
__global__ void tail_kernel(const void* __restrict__ Wq, const void* __restrict__ Wk,
                            const void* __restrict__ Ws, const void* __restrict__ bs,
                            const int* __restrict__ gidx, const int* __restrict__ gsrc,
                            const float* __restrict__ pool, void* __restrict__ out,
                            const int* __restrict__ flag) {
    int f = *flag;
    __shared__ float vq[128], vk[128];
    __shared__ float sq[4096], sk[4096];
    int tid = threadIdx.x;  // 256
    {
        int which = tid >> 7;
        int i = tid & 127;
        int h = i >> 5, dd = i & 31;
        const void* Wm = which ? Wk : Wq;
        float sum = 0.f;
#pragma unroll
        for (int o = 0; o < 32; o++)
            sum = fmaf(loadF(Wm, (h * 32 + dd) * 32 + o, f), loadF(Ws, h * 64 + which * 32 + o, f), sum);
        (which ? vk : vq)[i] = sum;
    }
    __syncthreads();
    for (int idx = tid; idx < 8192; idx += 256) {
        int which = idx >> 12;
        int i = idx & 4095;
        int g = i >> 2, h = i & 3;
        const float* V = which ? vk : vq;
        float s = 0.f;
#pragma unroll
        for (int dd = 0; dd < 32; dd++) s = fmaf(pool[g * 32 + dd], V[h * 32 + dd], s);
        (which ? sk : sq)[i] = s;
    }
    __syncthreads();
    for (int t = tid; t < 4096; t += 256) {
        int g = t >> 2, h = t & 3;
        int i = gidx[g];
        float bsv = loadF(bs, h, f);
        float sqi = sq[i * 4 + h];
        float trg = sigm(sqi + sk[i * 4 + h] + bsv);
        float ga[3];
#pragma unroll
        for (int q = 0; q < 3; q++) {
            int jj = gsrc[g * 4 + 1 + q];
            ga[q] = sigm(sqi + sk[jj * 4 + h] + bsv);
        }
        float ss = (ga[0] + ga[1] + ga[2]) * (1.f / 3.f);
        float mx = fmaxf(ss, trg);
        float e0 = __expf(ss - mx), e1 = __expf(trg - mx);
        float inv = 1.f / (e0 + e1);
        float tw0 = e0 * inv, tw1 = e1 * inv;
        float mg = fmaxf(ga[0], fmaxf(ga[1], ga[2]));
        float w0 = __expf(ga[0] - mg), w1 = __expf(ga[1] - mg), w2 = __expf(ga[2] - mg);
        float wi = tw0 * 3.f / (w0 + w1 + w2);
        storeF(out, g * 16 + 0 + h,  tw1,     f);
        storeF(out, g * 16 + 4 + h,  w0 * wi, f);
        storeF(out, g * 16 + 8 + h,  w1 * wi, f);
        storeF(out, g * 16 + 12 + h, w2 * wi, f);
    }
}

extern "C" void kernel_launch(void* const* d_in, const int* in_sizes, int n_in,
                              void* d_out, int out_size, void* d_ws, size_t ws_size,
                              hipStream_t stream) {
    // -------- inputs --------
    const void* x        = d_in[0];
    const int*  ei       = (const int*)d_in[1];
    const void* a2s_msg  = d_in[2];
    const void* a2s_hid  = d_in[3];
    const void* s2a_msg  = d_in[4];
    const void* s2a_hid  = d_in[5];
    const void* prefix   = d_in[6];
    const int*  fidx     = (const int*)d_in[7];
    const int*  gidx     = (const int*)d_in[8];
    const int*  gsrc     = (const int*)d_in[9];
    const void* g1_Wih   = d_in[10];
    const void* g1_Whh   = d_in[11];
    const void* g1_bih   = d_in[12];
    const void* g1_bhh   = d_in[13];
    const void* g2_Wih   = d_in[14];
    const void* g2_Whh   = d_in[15];
    const void* g2_bih   = d_in[16];
    const void* g2_bhh   = d_in[17];
    const void* W1  = d_in[18];
    const void* as1 = d_in[19];
    const void* ad1 = d_in[20];
    const void* b1  = d_in[21];
    const void* W2  = d_in[22];
    const void* as2 = d_in[23];
    const void* ad2 = d_in[24];
    const void* b2  = d_in[25];
    const void* W3  = d_in[26];
    const void* as3 = d_in[27];
    const void* ad3 = d_in[28];
    const void* b3  = d_in[29];
    const void* W4  = d_in[30];
    const void* as4 = d_in[31];
    const void* ad4 = d_in[32];
    const void* b4  = d_in[33];
    const void* Wq  = d_in[34];
    const void* Wk  = d_in[35];
    const void* Ws  = d_in[36];
    const void* bs  = d_in[37];

    const int* src_e = ei;
    const int* dst_e = ei + EED;

    // -------- workspace layout --------
    char* wp = (char*)d_ws;
    auto alloc = [&](size_t bytes) {
        char* p = wp;
        wp += (bytes + 255) & ~(size_t)255;
        return p;
    };
    int*   csr   = (int*)alloc((size_t)ETOT * 4);              // 8.8 MB
    int*   offs  = (int*)alloc((size_t)(NND + 1) * 4);         // 0.8 MB
    int*   gtail = (int*)alloc((size_t)NB * 4);
    int*   dflag = (int*)alloc(256);
    float* pool  = (float*)alloc((size_t)MMD * 32 * 4);
    bf16*  bufA  = (bf16*)alloc((size_t)NND * 32 * 2);         // 12.8 MB
    bf16*  bufB  = (bf16*)alloc((size_t)NND * 32 * 2);         // 12.8 MB
    unsigned int* stage = (unsigned int*)bufB;

    // -------- dtype detection + gtail zero --------
    detect_kernel<<<1, 64, 0, stream>>>(x, dflag, gtail);

    // -------- assemble xx0 into bufA (stride 16) --------
    assemble_kernel<<<(NXD * 19 + 255) / 256, 256, 0, stream>>>(x, prefix, bufA, dflag);
    gru2_kernel<<<392, 256, 0, stream>>>(a2s_msg, a2s_hid, g1_Wih, g1_Whh, g1_bih, g1_bhh,
                                         s2a_msg, s2a_hid, g2_Wih, g2_Whh, g2_bih, g2_bhh,
                                         d_out, bufA, dflag);

    // -------- CSR build: bin -> build --------
    bin_kernel<<<(ETOT + TILE - 1) / TILE, 256, 0, stream>>>(src_e, dst_e, gtail, stage);
    build_kernel<<<NB, 256, 0, stream>>>(stage, gtail, offs, csr);

    // -------- GAT layers 1..3 (ping-pong bufA <-> bufB) --------
    const int nblk_feat = NND / 8;   // 25000
    const int nblk_agg  = NND / 64;  // 3125
    feat_kernel<16><<<nblk_feat, 256, 0, stream>>>(bufA, W1, bufB, dflag);
    agg_kernel<<<nblk_agg, 256, 0, stream>>>(bufB, offs, csr, as1, ad1, b1, bufA, dflag);
    feat_kernel<32><<<nblk_feat, 256, 0, stream>>>(bufA, W2, bufB, dflag);
    agg_kernel<<<nblk_agg, 256, 0, stream>>>(bufB, offs, csr, as2, ad2, b2, bufA, dflag);
    feat_kernel<32><<<nblk_feat, 256, 0, stream>>>(bufA, W3, bufB, dflag);
    agg_kernel<<<nblk_agg, 256, 0, stream>>>(bufB, offs, csr, as3, ad3, b3, bufA, dflag);

    // -------- layer 4: edge-parallel, one block per pooled node --------
    layer4_kernel<<<MMD, 256, 0, stream>>>(bufA, W4, as4, ad4, b4, fidx, offs, csr, pool, dflag);

    // -------- fused final scoring --------
    tail_kernel<<<1, 256, 0, stream>>>(Wq, Wk, Ws, bs, gidx, gsrc, pool, d_out, dflag);
}

// Round 11
// 454.410 us; speedup vs baseline: 1.4462x; 1.0802x over previous
//
#include <hip/hip_runtime.h>
#include <hip/hip_bf16.h>

#define NXD   100000
#define AROWS 50000
#define NND   200000   // total nodes
#define EED   2000000  // given edges
#define ETOT  2200000  // + self loops
#define GHD   13
#define MMD   1024

#define OUT_H1 16384
#define OUT_H2 (16384 + AROWS * GHD)

#define NB    196      // buckets for CSR build (1024 nodes each)
#define BSH   10
#define CAP   16000    // staging capacity per bucket (mean 11264)
#define TILE  4096     // edges per bin-pass block (538 blocks)

typedef __hip_bfloat16 bf16;
typedef unsigned int uvec4 __attribute__((ext_vector_type(4)));

__device__ __forceinline__ float bf2f(bf16 v) { return __bfloat162float(v); }
__device__ __forceinline__ float sigm(float x) { return 1.f / (1.f + __expf(-x)); }
__device__ __forceinline__ float tanhfast(float x) {
    x = fminf(15.f, fmaxf(-15.f, x));
    float t = __expf(-2.f * x);
    return (1.f - t) / (1.f + t);
}
__device__ __forceinline__ float lrelu(float x, float s) { return x > 0.f ? x : s * x; }

__device__ __forceinline__ unsigned short f2bf_bits(float v) {
    bf16 b = __float2bfloat16(v);
    return *reinterpret_cast<unsigned short*>(&b);
}
__device__ __forceinline__ float bflo(unsigned int u) { return __uint_as_float((u & 0xFFFFu) << 16); }
__device__ __forceinline__ float bfhi(unsigned int u) { return __uint_as_float(u & 0xFFFF0000u); }

// Generic input load / output store: f32 flag picks fp32 vs bf16 interpretation.
__device__ __forceinline__ float loadF(const void* p, size_t i, int f32) {
    return f32 ? ((const float*)p)[i] : bf2f(((const bf16*)p)[i]);
}
__device__ __forceinline__ void storeF(void* p, size_t i, float v, int f32) {
    if (f32) ((float*)p)[i] = v;
    else ((bf16*)p)[i] = __float2bfloat16(v);
}

// ---------------- dtype detection + gtail zero ----------------
__global__ void detect_kernel(const void* __restrict__ xp, int* __restrict__ flag,
                              int* __restrict__ gtail) {
    int lane = threadIdx.x;  // 64
    const unsigned short* u = (const unsigned short*)xp;
    unsigned short b = u[lane * 2];
    int e = (b >> 7) & 0xFF;
    int viol = (e == 0xFF) || (e < 64) || (e > 190);
    unsigned long long mask = __ballot(viol != 0);
    if (lane == 0) flag[0] = (__popcll(mask) > 8) ? 1 : 0;  // 1 => fp32 inputs
    for (int i = lane; i < NB; i += 64) gtail[i] = 0;
}

// ---------------- x rows + prefix columns into bufA ----------------
__global__ void assemble_kernel(const void* __restrict__ x, const void* __restrict__ prefix,
                                bf16* __restrict__ bufA, const int* __restrict__ flag) {
    int f = *flag;
    int t = blockIdx.x * 256 + threadIdx.x;
    if (t < NXD * 16) {
        bufA[t] = __float2bfloat16(loadF(x, t, f));
    } else {
        int u = t - NXD * 16;
        if (u < NXD * 3) {
            int r = u / 3, c = u - r * 3;
            bufA[(size_t)(NXD + r) * 16 + c] = __float2bfloat16(loadF(prefix, u, f));
        }
    }
}

// ---------------- both GRUs in one kernel (50000 rows each, in=1, hidden=13) ----------------
__global__ void gru2_kernel(const void* __restrict__ msg1, const void* __restrict__ hid1,
                            const void* __restrict__ Wih1, const void* __restrict__ Whh1,
                            const void* __restrict__ bih1, const void* __restrict__ bhh1,
                            const void* __restrict__ msg2, const void* __restrict__ hid2,
                            const void* __restrict__ Wih2, const void* __restrict__ Whh2,
                            const void* __restrict__ bih2, const void* __restrict__ bhh2,
                            void* __restrict__ dout, bf16* __restrict__ xxA,
                            const int* __restrict__ flag) {
    int f = *flag;
    int which = blockIdx.x >= 196;
    const void* msg = which ? msg2 : msg1;
    const void* hid = which ? hid2 : hid1;
    const void* Wih = which ? Wih2 : Wih1;
    const void* Whh = which ? Whh2 : Whh1;
    const void* bih = which ? bih2 : bih1;
    const void* bhh = which ? bhh2 : bhh1;
    size_t houtbase = which ? (size_t)OUT_H2 : (size_t)OUT_H1;
    int rowbase = which ? AROWS : 0;
    int blk = blockIdx.x - (which ? 196 : 0);
    __shared__ float WhhL[39 * 13], WihL[39], bihL[39], bhhL[39];
    int tid = threadIdx.x;
    for (int i = tid; i < 39 * 13; i += 256) WhhL[i] = loadF(Whh, i, f);
    if (tid < 39) { WihL[tid] = loadF(Wih, tid, f); bihL[tid] = loadF(bih, tid, f); bhhL[tid] = loadF(bhh, tid, f); }
    __syncthreads();
    int n = blk * 256 + tid;
    if (n >= AROWS) return;
    float x = loadF(msg, n, f);
    float h[GHD];
#pragma unroll
    for (int k = 0; k < GHD; k++) h[k] = loadF(hid, n * GHD + k, f);
#pragma unroll
    for (int k = 0; k < GHD; k++) {
        float gir = fmaf(x, WihL[k],      bihL[k]);
        float giz = fmaf(x, WihL[13 + k], bihL[13 + k]);
        float gin = fmaf(x, WihL[26 + k], bihL[26 + k]);
        float ghr = bhhL[k], ghz = bhhL[13 + k], ghn = bhhL[26 + k];
#pragma unroll
        for (int q = 0; q < GHD; q++) {
            ghr = fmaf(h[q], WhhL[k * 13 + q],        ghr);
            ghz = fmaf(h[q], WhhL[(13 + k) * 13 + q], ghz);
            ghn = fmaf(h[q], WhhL[(26 + k) * 13 + q], ghn);
        }
        float r = sigm(gir + ghr);
        float z = sigm(giz + ghz);
        float nn = tanhfast(gin + r * ghn);
        float o = (1.f - z) * nn + z * h[k];
        storeF(dout, houtbase + (size_t)n * GHD + k, o, f);
        xxA[(size_t)(NXD + rowbase + n) * 16 + 3 + k] = __float2bfloat16(o);
    }
}

// ---------------- CSR build: bin pass ----------------
__global__ void bin_kernel(const int* __restrict__ src_e, const int* __restrict__ dst_e,
                           int* __restrict__ gtail, unsigned int* __restrict__ stage) {
    __shared__ int hist[NB];
    __shared__ int base[NB];
    __shared__ int cur[NB];
    int tid = threadIdx.x;
    for (int i = tid; i < NB; i += 256) hist[i] = 0;
    __syncthreads();
    int t0 = blockIdx.x * TILE;
    int tend = t0 + TILE; if (tend > ETOT) tend = ETOT;
    for (int t = t0 + tid; t < tend; t += 256) {
        int d = (t < EED) ? dst_e[t] : (t - EED);
        atomicAdd(&hist[d >> BSH], 1);
    }
    __syncthreads();
    for (int i = tid; i < NB; i += 256) {
        int c = hist[i];
        base[i] = (c > 0) ? atomicAdd(&gtail[i], c) : 0;
        cur[i] = 0;
    }
    __syncthreads();
    for (int t = t0 + tid; t < tend; t += 256) {
        int s, d;
        if (t < EED) { s = src_e[t]; d = dst_e[t]; } else { s = d = t - EED; }
        int b = d >> BSH;
        int p = base[b] + atomicAdd(&cur[b], 1);
        if (p < CAP)
            stage[(size_t)b * CAP + p] = ((unsigned int)(d & 1023) << 18) | (unsigned int)s;
    }
}

// ---------------- CSR build: per-bucket placement (ebase computed in-kernel) ----------------
__global__ void build_kernel(const unsigned int* __restrict__ stage,
                             const int* __restrict__ gtail,
                             int* __restrict__ offs, int* __restrict__ csr) {
    __shared__ int cnt[1024];
    __shared__ int loc[1024];
    __shared__ int cur[1024];
    __shared__ int lds[256];
    int b = blockIdx.x;
    int tid = threadIdx.x;
    int v = (tid < NB) ? gtail[tid] : 0;
    lds[tid] = v; __syncthreads();
    for (int off = 1; off < 256; off <<= 1) {
        int t2 = (tid >= off) ? lds[tid - off] : 0;
        __syncthreads();
        lds[tid] += t2;
        __syncthreads();
    }
    __shared__ int ebs;
    if (tid == b) ebs = lds[tid] - v;
    __syncthreads();
    int eb = ebs;
    int nE = gtail[b]; if (nE > CAP) nE = CAP;
    const unsigned int* st = stage + (size_t)b * CAP;
    for (int i = tid; i < 1024; i += 256) cnt[i] = 0;
    __syncthreads();
    for (int i = tid; i < nE; i += 256)
        atomicAdd(&cnt[st[i] >> 18], 1);
    __syncthreads();
    int c0 = cnt[tid * 4], c1 = cnt[tid * 4 + 1], c2 = cnt[tid * 4 + 2], c3 = cnt[tid * 4 + 3];
    int s = c0 + c1 + c2 + c3;
    lds[tid] = s; __syncthreads();
    for (int off = 1; off < 256; off <<= 1) {
        int t2 = (tid >= off) ? lds[tid - off] : 0;
        __syncthreads();
        lds[tid] += t2;
        __syncthreads();
    }
    int run = lds[tid] - s;
    loc[tid * 4]     = run;
    loc[tid * 4 + 1] = run + c0;
    loc[tid * 4 + 2] = run + c0 + c1;
    loc[tid * 4 + 3] = run + c0 + c1 + c2;
    __syncthreads();
    int nodebase = b << BSH;
    for (int i = tid; i < 1024; i += 256) {
        cur[i] = loc[i];
        int n = nodebase + i;
        if (n < NND) offs[n] = eb + loc[i];
    }
    if (b == 0 && tid == 0) offs[NND] = ETOT;
    __syncthreads();
    for (int i = tid; i < nE; i += 256) {
        unsigned int e = st[i];
        int dl = e >> 18;
        int src = e & 0x3FFFF;
        int p = atomicAdd(&cur[dl], 1);
        csr[eb + p] = src;
    }
}

// ---------------- per-layer features: h = xx@W, W column in VGPRs ----------------
// Lane j holds W[:,j] in registers (coalesced one-time load); each 32-lane
// half-wave computes 16 consecutive nodes. No LDS at all (old version was
// LDS-pipe bound: 32 ds_read per node ~ 30us of the 46us).
template <int K>
__global__ void feat_kernel(const bf16* __restrict__ xx,
                            const void* __restrict__ W,
                            bf16* __restrict__ hbuf, const int* __restrict__ flag) {
    int f = *flag;
    int tid = threadIdx.x;
    int j = tid & 31;
    float Wc[K];
#pragma unroll
    for (int k = 0; k < K; k++) Wc[k] = loadF(W, k * 32 + j, f);
    int half = blockIdx.x * 8 + (tid >> 5);
    if (half >= NND / 16) return;
    int n0 = half * 16;
#pragma unroll 4
    for (int n = n0; n < n0 + 16; n++) {
        const uvec4* xr4 = (const uvec4*)(xx + (size_t)n * K);
        float v = 0.f;
#pragma unroll
        for (int q = 0; q < K / 8; q++) {
            uvec4 u = xr4[q];
            v = fmaf(bflo(u.x), Wc[q * 8 + 0], v);
            v = fmaf(bfhi(u.x), Wc[q * 8 + 1], v);
            v = fmaf(bflo(u.y), Wc[q * 8 + 2], v);
            v = fmaf(bfhi(u.y), Wc[q * 8 + 3], v);
            v = fmaf(bflo(u.z), Wc[q * 8 + 4], v);
            v = fmaf(bfhi(u.z), Wc[q * 8 + 5], v);
            v = fmaf(bflo(u.w), Wc[q * 8 + 6], v);
            v = fmaf(bfhi(u.w), Wc[q * 8 + 7], v);
        }
        hbuf[(size_t)n * 32 + j] = __float2bfloat16(v);
    }
}

// ---------------- aggregation (layers 1-3): segment softmax ----------------
__global__ void agg_kernel(const bf16* __restrict__ hbuf, const int* __restrict__ offs,
                           const int* __restrict__ csr, const void* __restrict__ asrc,
                           const void* __restrict__ adst, const void* __restrict__ bias,
                           bf16* __restrict__ xxout, const int* __restrict__ flag) {
    int f = *flag;
    __shared__ float bl[32], asl[32], adl[32];
    int tid = threadIdx.x;
    if (tid < 32) {
        bl[tid]  = loadF(bias, tid, f);
        asl[tid] = loadF(asrc, tid, f);
        adl[tid] = loadF(adst, tid, f);
    }
    __syncthreads();
    int n = blockIdx.x * 64 + (tid >> 2);
    int j = tid & 3;                 // head j, channels 8j..8j+7
    int cb = 8 * j;
    float A0 = asl[cb], A1 = asl[cb + 1], A2 = asl[cb + 2], A3 = asl[cb + 3];
    float A4 = asl[cb + 4], A5 = asl[cb + 5], A6 = asl[cb + 6], A7 = asl[cb + 7];
    uvec4 hd = *(const uvec4*)(hbuf + (size_t)n * 32 + cb);
    float adv = bflo(hd.x) * adl[cb]     + bfhi(hd.x) * adl[cb + 1]
              + bflo(hd.y) * adl[cb + 2] + bfhi(hd.y) * adl[cb + 3]
              + bflo(hd.z) * adl[cb + 4] + bfhi(hd.z) * adl[cb + 5]
              + bflo(hd.w) * adl[cb + 6] + bfhi(hd.w) * adl[cb + 7];
    int beg = offs[n], end = offs[n + 1];
    int cnt = end - beg;
    const int* cp = csr + beg;
    int s0 = cp[0];
    uvec4 h0 = *(const uvec4*)(hbuf + (size_t)s0 * 32 + cb);
    uvec4 h1 = h0;
    if (cnt > 1) {
        int s1 = cp[1];
        h1 = *(const uvec4*)(hbuf + (size_t)s1 * 32 + cb);
    }
    float den = 0.f;
    float a0 = 0.f, a1 = 0.f, a2 = 0.f, a3 = 0.f, a4 = 0.f, a5 = 0.f, a6 = 0.f, a7 = 0.f;
    for (int i = 0; i < cnt; i++) {
        uvec4 hn = (uvec4)(0u);
        if (i + 2 < cnt) {
            int sn = cp[i + 2];
            hn = *(const uvec4*)(hbuf + (size_t)sn * 32 + cb);
        }
        float v0 = bflo(h0.x), v1 = bfhi(h0.x), v2 = bflo(h0.y), v3 = bfhi(h0.y);
        float v4 = bflo(h0.z), v5 = bfhi(h0.z), v6 = bflo(h0.w), v7 = bfhi(h0.w);
        float as = v0 * A0 + v1 * A1 + v2 * A2 + v3 * A3
                 + v4 * A4 + v5 * A5 + v6 * A6 + v7 * A7;
        float e = as + adv;
        e = e > 0.f ? e : 0.2f * e;
        e = fminf(50.f, fmaxf(-50.f, e));
        float w = __expf(e);
        den += w;
        a0 = fmaf(w, v0, a0); a1 = fmaf(w, v1, a1);
        a2 = fmaf(w, v2, a2); a3 = fmaf(w, v3, a3);
        a4 = fmaf(w, v4, a4); a5 = fmaf(w, v5, a5);
        a6 = fmaf(w, v6, a6); a7 = fmaf(w, v7, a7);
        h0 = h1; h1 = hn;
    }
    float inv = 1.f / den;
    float o0 = lrelu(fmaf(a0, inv, bl[cb + 0]), 0.01f);
    float o1 = lrelu(fmaf(a1, inv, bl[cb + 1]), 0.01f);
    float o2 = lrelu(fmaf(a2, inv, bl[cb + 2]), 0.01f);
    float o3 = lrelu(fmaf(a3, inv, bl[cb + 3]), 0.01f);
    float o4 = lrelu(fmaf(a4, inv, bl[cb + 4]), 0.01f);
    float o5 = lrelu(fmaf(a5, inv, bl[cb + 5]), 0.01f);
    float o6 = lrelu(fmaf(a6, inv, bl[cb + 6]), 0.01f);
    float o7 = lrelu(fmaf(a7, inv, bl[cb + 7]), 0.01f);
    uvec4 p;
    p.x = ((unsigned int)f2bf_bits(o1) << 16) | f2bf_bits(o0);
    p.y = ((unsigned int)f2bf_bits(o3) << 16) | f2bf_bits(o2);
    p.z = ((unsigned int)f2bf_bits(o5) << 16) | f2bf_bits(o4);
    p.w = ((unsigned int)f2bf_bits(o7) << 16) | f2bf_bits(o6);
    __builtin_nontemporal_store(p, (uvec4*)(xxout + (size_t)n * 32 + cb));
}

// ---------------- layer 4: edge-parallel, one block per function node ----------------
__global__ void layer4_kernel(const bf16* __restrict__ xx,
                              const void* __restrict__ W4,
                              const void* __restrict__ asrc,
                              const void* __restrict__ adst,
                              const void* __restrict__ b4,
                              const int* __restrict__ fidx, const int* __restrict__ offs,
                              const int* __restrict__ csr, float* __restrict__ pool,
                              const int* __restrict__ flag) {
    int f = *flag;
    __shared__ float Wl[32 * 128];
    __shared__ float asl[128], adl[128], bl[32];
    __shared__ float accs[4][32];
    __shared__ float dens[4];
    int tid = threadIdx.x;
    for (int i = tid; i < 32 * 128; i += 256) Wl[i] = loadF(W4, i, f);
    if (tid < 128) { asl[tid] = loadF(asrc, tid, f); adl[tid] = loadF(adst, tid, f); accs[tid >> 5][tid & 31] = 0.f; }
    if (tid < 32) bl[tid] = loadF(b4, tid, f);
    if (tid < 4) dens[tid] = 0.f;
    __syncthreads();
    int g = blockIdx.x;
    int d = fidx[g];
    int wave = tid >> 6, lane = tid & 63;
    int c = lane & 31;
    int h0 = lane >> 5;
    int h1 = h0 + 2;
    const uvec4* xd4 = (const uvec4*)(xx + (size_t)d * 32);
    uvec4 du0 = xd4[0], du1 = xd4[1];
    float v0 = 0.f, v1 = 0.f;
    {
        unsigned int us[8] = {du0.x, du0.y, du0.z, du0.w, du1.x, du1.y, du1.z, du1.w};
#pragma unroll
        for (int q = 0; q < 8; q++) {
            unsigned int u = us[q];
            int k = 2 * q;
            v0 = fmaf(bflo(u), Wl[k * 128 + lane], v0);       v0 = fmaf(bfhi(u), Wl[(k + 1) * 128 + lane], v0);
            v1 = fmaf(bflo(u), Wl[k * 128 + lane + 64], v1);  v1 = fmaf(bfhi(u), Wl[(k + 1) * 128 + lane + 64], v1);
        }
    }
    float ad0 = v0 * adl[h0 * 32 + c];
    float ad1 = v1 * adl[h1 * 32 + c];
#pragma unroll
    for (int mk = 1; mk < 32; mk <<= 1) { ad0 += __shfl_xor(ad0, mk); ad1 += __shfl_xor(ad1, mk); }
    int beg = offs[d], end = offs[d + 1];
    float den0 = 0.f, den1 = 0.f, acc0 = 0.f, acc1 = 0.f;
    for (int i = beg + wave; i < end; i += 4) {
        int s = csr[i];
        const uvec4* xs4 = (const uvec4*)(xx + (size_t)s * 32);
        uvec4 su0 = xs4[0], su1 = xs4[1];
        float s0 = 0.f, s1 = 0.f;
        unsigned int us[8] = {su0.x, su0.y, su0.z, su0.w, su1.x, su1.y, su1.z, su1.w};
#pragma unroll
        for (int q = 0; q < 8; q++) {
            unsigned int u = us[q];
            int k = 2 * q;
            s0 = fmaf(bflo(u), Wl[k * 128 + lane], s0);       s0 = fmaf(bfhi(u), Wl[(k + 1) * 128 + lane], s0);
            s1 = fmaf(bflo(u), Wl[k * 128 + lane + 64], s1);  s1 = fmaf(bfhi(u), Wl[(k + 1) * 128 + lane + 64], s1);
        }
        float as0 = s0 * asl[h0 * 32 + c];
        float as1 = s1 * asl[h1 * 32 + c];
#pragma unroll
        for (int mk = 1; mk < 32; mk <<= 1) { as0 += __shfl_xor(as0, mk); as1 += __shfl_xor(as1, mk); }
        float e0 = lrelu(as0 + ad0, 0.2f);
        float e1 = lrelu(as1 + ad1, 0.2f);
        e0 = fminf(50.f, fmaxf(-50.f, e0));
        e1 = fminf(50.f, fmaxf(-50.f, e1));
        float w0 = __expf(e0), w1 = __expf(e1);
        den0 += w0; acc0 = fmaf(w0, s0, acc0);
        den1 += w1; acc1 = fmaf(w1, s1, acc1);
    }
    atomicAdd(&accs[h0][c], acc0);
    atomicAdd(&accs[h1][c], acc1);
    if (c == 0) { atomicAdd(&dens[h0], den0); atomicAdd(&dens[h1], den1); }
    __syncthreads();
    if (tid < 32) {
        float t = accs[0][tid] / dens[0] + accs[1][tid] / dens[1]
                + accs[2][tid] / dens[2] + accs[3][tid] / dens[3];
        float o = t * 0.25f + bl[tid];
        pool[g * 32 + tid] = lrelu(o, 0.01f);
    }
}

// ---------------- fused final scoring: vq/vk + sq/sk + weights (one block) ----------------
__global__ void tail_kernel(const void* __restrict__ Wq, const void* __restrict__ Wk,
                            const void* __restrict__ Ws, const void* __restrict__ bs,
                            const int* __restrict__ gidx, const int* __restrict__ gsrc,
                            const float* __restrict__ pool, void* __restrict__ out,
                            const int* __restrict__ flag) {
    int f = *flag;
    __shared__ float vq[128], vk[128];
    __shared__ float sq[4096], sk[4096];
    int tid = threadIdx.x;  // 256
    {
        int which = tid >> 7;
        int i = tid & 127;
        int h = i >> 5, dd = i & 31;
        const void* Wm = which ? Wk : Wq;
        float sum = 0.f;
#pragma unroll
        for (int o = 0; o < 32; o++)
            sum = fmaf(loadF(Wm, (h * 32 + dd) * 32 + o, f), loadF(Ws, h * 64 + which * 32 + o, f), sum);
        (which ? vk : vq)[i] = sum;
    }
    __syncthreads();
    for (int idx = tid; idx < 8192; idx += 256) {
        int which = idx >> 12;
        int i = idx & 4095;
        int g = i >> 2, h = i & 3;
        const float* V = which ? vk : vq;
        float s = 0.f;
#pragma unroll
        for (int dd = 0; dd < 32; dd++) s = fmaf(pool[g * 32 + dd], V[h * 32 + dd], s);
        (which ? sk : sq)[i] = s;
    }
    __syncthreads();
    for (int t = tid; t < 4096; t += 256) {
        int g = t >> 2, h = t & 3;
        int i = gidx[g];
        float bsv = loadF(bs, h, f);
        float sqi = sq[i * 4 + h];
        float trg = sigm(sqi + sk[i * 4 + h] + bsv);
        float ga[3];
#pragma unroll
        for (int q = 0; q < 3; q++) {
            int jj = gsrc[g * 4 + 1 + q];
            ga[q] = sigm(sqi + sk[jj * 4 + h] + bsv);
        }
        float ss = (ga[0] + ga[1] + ga[2]) * (1.f / 3.f);
        float mx = fmaxf(ss, trg);
        float e0 = __expf(ss - mx), e1 = __expf(trg - mx);
        float inv = 1.f / (e0 + e1);
        float tw0 = e0 * inv, tw1 = e1 * inv;
        float mg = fmaxf(ga[0], fmaxf(ga[1], ga[2]));
        float w0 = __expf(ga[0] - mg), w1 = __expf(ga[1] - mg), w2 = __expf(ga[2] - mg);
        float wi = tw0 * 3.f / (w0 + w1 + w2);
        storeF(out, g * 16 + 0 + h,  tw1,     f);
        storeF(out, g * 16 + 4 + h,  w0 * wi, f);
        storeF(out, g * 16 + 8 + h,  w1 * wi, f);
        storeF(out, g * 16 + 12 + h, w2 * wi, f);
    }
}

extern "C" void kernel_launch(void* const* d_in, const int* in_sizes, int n_in,
                              void* d_out, int out_size, void* d_ws, size_t ws_size,
                              hipStream_t stream) {
    // -------- inputs --------
    const void* x        = d_in[0];
    const int*  ei       = (const int*)d_in[1];
    const void* a2s_msg  = d_in[2];
    const void* a2s_hid  = d_in[3];
    const void* s2a_msg  = d_in[4];
    const void* s2a_hid  = d_in[5];
    const void* prefix   = d_in[6];
    const int*  fidx     = (const int*)d_in[7];
    const int*  gidx     = (const int*)d_in[8];
    const int*  gsrc     = (const int*)d_in[9];
    const void* g1_Wih   = d_in[10];
    const void* g1_Whh   = d_in[11];
    const void* g1_bih   = d_in[12];
    const void* g1_bhh   = d_in[13];
    const void* g2_Wih   = d_in[14];
    const void* g2_Whh   = d_in[15];
    const void* g2_bih   = d_in[16];
    const void* g2_bhh   = d_in[17];
    const void* W1  = d_in[18];
    const void* as1 = d_in[19];
    const void* ad1 = d_in[20];
    const void* b1  = d_in[21];
    const void* W2  = d_in[22];
    const void* as2 = d_in[23];
    const void* ad2 = d_in[24];
    const void* b2  = d_in[25];
    const void* W3  = d_in[26];
    const void* as3 = d_in[27];
    const void* ad3 = d_in[28];
    const void* b3  = d_in[29];
    const void* W4  = d_in[30];
    const void* as4 = d_in[31];
    const void* ad4 = d_in[32];
    const void* b4  = d_in[33];
    const void* Wq  = d_in[34];
    const void* Wk  = d_in[35];
    const void* Ws  = d_in[36];
    const void* bs  = d_in[37];

    const int* src_e = ei;
    const int* dst_e = ei + EED;

    // -------- workspace layout --------
    char* wp = (char*)d_ws;
    auto alloc = [&](size_t bytes) {
        char* p = wp;
        wp += (bytes + 255) & ~(size_t)255;
        return p;
    };
    int*   csr   = (int*)alloc((size_t)ETOT * 4);              // 8.8 MB
    int*   offs  = (int*)alloc((size_t)(NND + 1) * 4);         // 0.8 MB
    int*   gtail = (int*)alloc((size_t)NB * 4);
    int*   dflag = (int*)alloc(256);
    float* pool  = (float*)alloc((size_t)MMD * 32 * 4);
    bf16*  bufA  = (bf16*)alloc((size_t)NND * 32 * 2);         // 12.8 MB
    bf16*  bufB  = (bf16*)alloc((size_t)NND * 32 * 2);         // 12.8 MB
    unsigned int* stage = (unsigned int*)bufB;

    // -------- dtype detection + gtail zero --------
    detect_kernel<<<1, 64, 0, stream>>>(x, dflag, gtail);

    // -------- assemble xx0 into bufA (stride 16) --------
    assemble_kernel<<<(NXD * 19 + 255) / 256, 256, 0, stream>>>(x, prefix, bufA, dflag);
    gru2_kernel<<<392, 256, 0, stream>>>(a2s_msg, a2s_hid, g1_Wih, g1_Whh, g1_bih, g1_bhh,
                                         s2a_msg, s2a_hid, g2_Wih, g2_Whh, g2_bih, g2_bhh,
                                         d_out, bufA, dflag);

    // -------- CSR build: bin -> build --------
    bin_kernel<<<(ETOT + TILE - 1) / TILE, 256, 0, stream>>>(src_e, dst_e, gtail, stage);
    build_kernel<<<NB, 256, 0, stream>>>(stage, gtail, offs, csr);

    // -------- GAT layers 1..3 (ping-pong bufA <-> bufB) --------
    const int nblk_feat = (NND / 16 + 7) / 8;  // 1563 (half-wave = 16 nodes)
    const int nblk_agg  = NND / 64;            // 3125
    feat_kernel<16><<<nblk_feat, 256, 0, stream>>>(bufA, W1, bufB, dflag);
    agg_kernel<<<nblk_agg, 256, 0, stream>>>(bufB, offs, csr, as1, ad1, b1, bufA, dflag);
    feat_kernel<32><<<nblk_feat, 256, 0, stream>>>(bufA, W2, bufB, dflag);
    agg_kernel<<<nblk_agg, 256, 0, stream>>>(bufB, offs, csr, as2, ad2, b2, bufA, dflag);
    feat_kernel<32><<<nblk_feat, 256, 0, stream>>>(bufA, W3, bufB, dflag);
    agg_kernel<<<nblk_agg, 256, 0, stream>>>(bufB, offs, csr, as3, ad3, b3, bufA, dflag);

    // -------- layer 4: edge-parallel, one block per pooled node --------
    layer4_kernel<<<MMD, 256, 0, stream>>>(bufA, W4, as4, ad4, b4, fidx, offs, csr, pool, dflag);

    // -------- fused final scoring --------
    tail_kernel<<<1, 256, 0, stream>>>(Wq, Wk, Ws, bs, gidx, gsrc, pool, d_out, dflag);
}